// Round 9
// baseline (374.067 us; speedup 1.0000x reference)
//
#include <hip/hip_runtime.h>
#include <math.h>

#define N_NODES 100000
#define N_EDGES 1600000
#define ROWB    512                 // bytes per row slot in d_out
#define HALFB   51200000ull         // byte offset of second output (sigma half)
#define NBKT    196                 // sort buckets (512 dst nodes each)
#define BSH     9
#define BCAP    10240               // entries per bucket (mean 8192, >20 sigma margin)
#define EPB     1024                // edges per bin block

typedef float  f32x4  __attribute__((ext_vector_type(4)));
typedef __bf16 bf16x8 __attribute__((ext_vector_type(8)));
typedef short  s16x8  __attribute__((ext_vector_type(8)));
typedef unsigned long long u64;

__device__ __forceinline__ unsigned short f2bf(float f) {
    unsigned int u = __builtin_bit_cast(unsigned int, f);
    u += 0x7FFFu + ((u >> 16) & 1u);          // RNE
    return (unsigned short)(u >> 16);
}
__device__ __forceinline__ float bf2f(unsigned short h) {
    unsigned int u = ((unsigned int)h) << 16;
    return __builtin_bit_cast(float, u);
}
__device__ __forceinline__ float bf_lo(unsigned int u) {
    return __builtin_bit_cast(float, u << 16);
}
__device__ __forceinline__ float bf_hi(unsigned int u) {
    return __builtin_bit_cast(float, u & 0xFFFF0000u);
}
__device__ __forceinline__ bf16x8 packhi(const float4& a, const float4& b) {
    float v[8] = {a.x, a.y, a.z, a.w, b.x, b.y, b.z, b.w};
    s16x8 hh;
    #pragma unroll
    for (int j = 0; j < 8; j++) hh[j] = (short)f2bf(v[j]);
    return __builtin_bit_cast(bf16x8, hh);
}

#define MFMA16(a, b, c) __builtin_amdgcn_mfma_f32_16x16x32_bf16((a), (b), (c), 0, 0, 0)

// ---------------- sort pass B: bucket-binning ----------------

__launch_bounds__(256)
__global__ void bin_kernel(const int* __restrict__ row, const int* __restrict__ col,
                           int* __restrict__ gcur, u64* __restrict__ entries) {
    __shared__ int hist[NBKT], base[NBKT], cur[NBKT];
    const int tid = threadIdx.x;
    for (int i = tid; i < NBKT; i += 256) { hist[i] = 0; cur[i] = 0; }
    __syncthreads();
    const int e0 = blockIdx.x * EPB;
    int cols[4];
    #pragma unroll
    for (int it = 0; it < 4; it++) {
        int e = e0 + it * 256 + tid;
        int c = (e < N_EDGES) ? col[e] : -1;
        cols[it] = c;
        if (c >= 0) atomicAdd(&hist[c >> BSH], 1);
    }
    __syncthreads();
    for (int i = tid; i < NBKT; i += 256)
        base[i] = atomicAdd(&gcur[i], hist[i]);
    __syncthreads();
    #pragma unroll
    for (int it = 0; it < 4; it++) {
        int e = e0 + it * 256 + tid;
        int c = cols[it];
        if (c >= 0) {
            int b = c >> BSH;
            int r = atomicAdd(&cur[b], 1);
            entries[(size_t)b * BCAP + base[b] + r] =
                ((u64)(unsigned)c << 32) | (unsigned)row[e];
        }
    }
}

// ---------------- bucket-base scan (196 values, 1 block) ----------------

__global__ void bktscan_kernel(const int* __restrict__ gcur, int* __restrict__ bktBase) {
    __shared__ int s[256];
    const int tid = threadIdx.x;
    int v = (tid < NBKT) ? gcur[tid] : 0;
    s[tid] = v;
    __syncthreads();
    for (int d = 1; d < 256; d <<= 1) {
        int t = (tid >= d) ? s[tid - d] : 0;
        __syncthreads();
        s[tid] += t;
        __syncthreads();
    }
    if (tid < NBKT) bktBase[tid] = s[tid] - v;
}

// ---------------- sort pass C: per-bucket histogram + scan + scatter ----------------

__launch_bounds__(256)
__global__ void csr_kernel(const u64* __restrict__ entries, const int* __restrict__ gcur,
                           const int* __restrict__ bktBase,
                           int* __restrict__ cnt, int* __restrict__ offs,
                           float* __restrict__ dinv, int* __restrict__ sortedRow) {
    __shared__ int lcnt[512], sA[512], sB[512], lcur[512];
    const int b = blockIdx.x, tid = threadIdx.x;
    const int n0 = b << BSH;
    lcnt[tid] = 0; lcnt[tid + 256] = 0;
    __syncthreads();
    const int nb = gcur[b], base = bktBase[b];
    const u64* ep = entries + (size_t)b * BCAP;
    for (int i = tid; i < nb; i += 256)
        atomicAdd(&lcnt[(int)(ep[i] >> 32) - n0], 1);
    __syncthreads();
    sA[tid] = lcnt[tid]; sA[tid + 256] = lcnt[tid + 256];
    __syncthreads();
    int* src = sA; int* dst = sB;
    for (int d = 1; d < 512; d <<= 1) {
        #pragma unroll
        for (int k = tid; k < 512; k += 256)
            dst[k] = src[k] + ((k >= d) ? src[k - d] : 0);
        __syncthreads();
        int* t = src; src = dst; dst = t;
    }
    #pragma unroll
    for (int k = tid; k < 512; k += 256) {
        int excl = src[k] - lcnt[k];
        lcur[k] = excl;
        int node = n0 + k;
        if (node < N_NODES) {
            offs[node] = base + excl;
            cnt[node]  = lcnt[k];
            dinv[node] = rsqrtf((float)(lcnt[k] + 1));   // +1 self loop
        }
    }
    __syncthreads();
    for (int i = tid; i < nb; i += 256) {
        u64 pk = ep[i];
        int local = (int)(pk >> 32) - n0;
        int p = base + atomicAdd(&lcur[local], 1);
        sortedRow[p] = (int)(pk & 0xFFFFFFFFu);
    }
}

// ---------------- weight pre-transpose ----------------

__global__ void prep_w(const float* __restrict__ W0, const float* __restrict__ Wmu,
                       const float* __restrict__ Wsig,
                       unsigned short* __restrict__ W0h, unsigned short* __restrict__ W0l,
                       unsigned short* __restrict__ Wmsh, unsigned short* __restrict__ Wmsl) {
    int c = blockIdx.x;
    int k = threadIdx.x;
    if (c < 128) {                               // W0 [256][128] -> [128 cols][256 k]
        float v = W0[k * 128 + c];
        unsigned short h = f2bf(v);
        W0h[c * 256 + k] = h;
        W0l[c * 256 + k] = f2bf(v - bf2f(h));
    } else if (k < 128) {                        // Wmu|Wsig -> [256 cols][128 k]
        int c2 = c - 128;
        float v = (c2 < 128) ? Wmu[k * 128 + c2] : Wsig[k * 128 + (c2 - 128)];
        unsigned short h = f2bf(v);
        Wmsh[c2 * 128 + k] = h;
        Wmsl[c2 * 128 + k] = f2bf(v - bf2f(h));
    }
}

// ---------------- GEMM1: t0_bf16 = x @ W0 (2-term W compensation, A=W) ----------------
// Wave owns 32 nodes; no LDS, no barriers. W hi/lo frags streamed from L2 in 8-load
// batches per col-tile; x rows prefetched and packed to bf16 per K-half.

__launch_bounds__(128)
__global__ void gemm1_mfma(const float* __restrict__ x,
                           const unsigned short* __restrict__ Wh,
                           const unsigned short* __restrict__ Wl,
                           char* __restrict__ outc) {
    const int lane = threadIdx.x & 63;
    const int gw = blockIdx.x * 2 + (threadIdx.x >> 6);
    const int r0 = gw * 32;
    if (r0 >= N_NODES) return;
    const int lrow = lane & 15, lk8 = (lane >> 4) * 8, fq = (lane >> 4) * 4;
    const int node0 = r0 + lrow, node1 = node0 + 16;

    const float* xp0 = x + (size_t)node0 * 256 + lk8;
    const float* xp1 = x + (size_t)node1 * 256 + lk8;

    f32x4 acc0[8] = {}, acc1[8] = {};
    for (int kh = 0; kh < 2; kh++) {
        bf16x8 xb0[4], xb1[4];
        #pragma unroll
        for (int s = 0; s < 4; s++) {
            float4 p0 = *(const float4*)(xp0 + kh * 128 + s * 32);
            float4 p1 = *(const float4*)(xp0 + kh * 128 + s * 32 + 4);
            xb0[s] = packhi(p0, p1);
            float4 q0 = *(const float4*)(xp1 + kh * 128 + s * 32);
            float4 q1 = *(const float4*)(xp1 + kh * 128 + s * 32 + 4);
            xb1[s] = packhi(q0, q1);
        }
        #pragma unroll 2
        for (int ct = 0; ct < 8; ct++) {
            const unsigned short* wph = Wh + (ct * 16 + lrow) * 256 + kh * 128 + lk8;
            const unsigned short* wpl = Wl + (ct * 16 + lrow) * 256 + kh * 128 + lk8;
            bf16x8 wh[4], wl[4];
            #pragma unroll
            for (int s = 0; s < 4; s++) {
                wh[s] = *(const bf16x8*)(wph + s * 32);
                wl[s] = *(const bf16x8*)(wpl + s * 32);
            }
            #pragma unroll
            for (int s = 0; s < 4; s++) {
                acc0[ct] = MFMA16(wh[s], xb0[s], acc0[ct]);
                acc1[ct] = MFMA16(wh[s], xb1[s], acc1[ct]);
                acc0[ct] = MFMA16(wl[s], xb0[s], acc0[ct]);
                acc1[ct] = MFMA16(wl[s], xb1[s], acc1[ct]);
            }
        }
    }
    char* d0 = outc + (size_t)node0 * ROWB + 256;
    char* d1 = outc + (size_t)node1 * ROWB + 256;
    #pragma unroll
    for (int ct = 0; ct < 8; ct++) {
        int f0 = ct * 16 + fq;
        ushort4 pa = make_ushort4(f2bf(acc0[ct][0]), f2bf(acc0[ct][1]),
                                  f2bf(acc0[ct][2]), f2bf(acc0[ct][3]));
        *(ushort4*)(d0 + f0 * 2) = pa;
        ushort4 pb = make_ushort4(f2bf(acc1[ct][0]), f2bf(acc1[ct][1]),
                                  f2bf(acc1[ct][2]), f2bf(acc1[ct][3]));
        *(ushort4*)(d1 + f0 * 2) = pb;
    }
}

// ---------------- aggregation: scalarized edge processing ------------------------------
// Edge ids/weights are wave-uniform: readlane -> SGPR bases (SALU addr math, s_load for
// dinv). Per-edge VALU = 2 unpack + 2 FMA + 1 mul. 8 gathers in flight per batch.

template <int EPI>
__launch_bounds__(256)
__global__ void agg_bf16(const char* __restrict__ srcBase, char* __restrict__ dstBase,
                         const int* __restrict__ offs, const int* __restrict__ cnt,
                         const int* __restrict__ sortedRow, const float* __restrict__ dinv,
                         const float* __restrict__ bias) {
    const int n = blockIdx.x * 4 + (threadIdx.x >> 6);
    const int lane = threadIdx.x & 63;
    const int laneB = lane * 4;
    const float dn = dinv[n];
    unsigned int u = *(const unsigned int*)(srcBase + (size_t)n * ROWB + laneB);
    const float ws = dn * dn;
    float acc0 = ws * bf_lo(u);
    float acc1 = ws * bf_hi(u);
    const int start = __builtin_amdgcn_readfirstlane(offs[n]);
    const int num   = __builtin_amdgcn_readfirstlane(cnt[n]);

    int i = 0;
    for (; i + 8 <= num; i += 8) {
        int myr = sortedRow[start + i + (lane & 7)];
        int rs[8];
        #pragma unroll
        for (int j = 0; j < 8; j++) rs[j] = __builtin_amdgcn_readlane(myr, j);
        unsigned int ue[8];
        #pragma unroll
        for (int j = 0; j < 8; j++) {
            const char* p = srcBase + ((size_t)rs[j] << 9);   // SGPR base
            ue[j] = *(const unsigned int*)(p + laneB);
        }
        float w[8];
        #pragma unroll
        for (int j = 0; j < 8; j++) w[j] = dn * dinv[rs[j]];
        #pragma unroll
        for (int j = 0; j < 8; j++) {
            acc0 = fmaf(w[j], bf_lo(ue[j]), acc0);
            acc1 = fmaf(w[j], bf_hi(ue[j]), acc1);
        }
    }
    for (; i < num; i++) {
        int rsv = __builtin_amdgcn_readfirstlane(sortedRow[start + i]);
        const char* p = srcBase + ((size_t)rsv << 9);
        unsigned int ue = *(const unsigned int*)(p + laneB);
        float w = dn * dinv[rsv];
        acc0 = fmaf(w, bf_lo(ue), acc0);
        acc1 = fmaf(w, bf_hi(ue), acc1);
    }

    if (EPI) {
        acc0 = fmaxf(acc0 + bias[2 * lane], 0.f);
        acc1 = fmaxf(acc1 + bias[2 * lane + 1], 0.f);
    }
    unsigned int o = (unsigned int)f2bf(acc0) | ((unsigned int)f2bf(acc1) << 16);
    *(unsigned int*)(dstBase + (size_t)n * ROWB + laneB) = o;
}

// ---------------- GEMM2: [mu|sigma] = t2 @ [Wmu|Wsig] (2-term, A=W) --------------------
// Wave owns 32 nodes; t2 rows prefetched to regs (consumed before mu overwrite -> safe);
// W frags streamed from L2; no LDS/barriers; per-col-tile fused epilogue.

__launch_bounds__(128)
__global__ void gemm2_mfma(const unsigned short* __restrict__ Wh,
                           const unsigned short* __restrict__ Wl,
                           const float* __restrict__ bmu, const float* __restrict__ bsig,
                           char* __restrict__ outc) {
    const int lane = threadIdx.x & 63;
    const int gw = blockIdx.x * 2 + (threadIdx.x >> 6);
    const int r0 = gw * 32;
    if (r0 >= N_NODES) return;
    const int lrow = lane & 15, lk8 = (lane >> 4) * 8, fq = (lane >> 4) * 4;
    const int node0 = r0 + lrow, node1 = node0 + 16;

    bf16x8 b0[4], b1[4];
    {
        const char* a0 = outc + (size_t)node0 * ROWB + lk8 * 2;
        const char* a1 = outc + (size_t)node1 * ROWB + lk8 * 2;
        #pragma unroll
        for (int ki = 0; ki < 4; ki++) {
            b0[ki] = *(const bf16x8*)(a0 + ki * 64);
            b1[ki] = *(const bf16x8*)(a1 + ki * 64);
        }
    }
    char* mu0 = outc + (size_t)node0 * ROWB;
    char* mu1 = outc + (size_t)node1 * ROWB;
    char* sg0 = outc + HALFB + (size_t)node0 * ROWB;
    char* sg1 = outc + HALFB + (size_t)node1 * ROWB;

    #pragma unroll 2
    for (int ct = 0; ct < 8; ct++) {            // mu half (cols 0..127)
        const unsigned short* wph = Wh + (ct * 16 + lrow) * 128 + lk8;
        const unsigned short* wpl = Wl + (ct * 16 + lrow) * 128 + lk8;
        bf16x8 wh[4], wl[4];
        #pragma unroll
        for (int ki = 0; ki < 4; ki++) {
            wh[ki] = *(const bf16x8*)(wph + ki * 32);
            wl[ki] = *(const bf16x8*)(wpl + ki * 32);
        }
        f32x4 aA = {}, aB = {};
        #pragma unroll
        for (int ki = 0; ki < 4; ki++) {
            aA = MFMA16(wh[ki], b0[ki], aA);
            aB = MFMA16(wh[ki], b1[ki], aB);
            aA = MFMA16(wl[ki], b0[ki], aA);
            aB = MFMA16(wl[ki], b1[ki], aB);
        }
        int f0 = ct * 16 + fq;
        float4 bv = *(const float4*)(bmu + f0);
        *(float4*)(mu0 + f0 * 4) = make_float4(aA[0] + bv.x, aA[1] + bv.y,
                                               aA[2] + bv.z, aA[3] + bv.w);
        *(float4*)(mu1 + f0 * 4) = make_float4(aB[0] + bv.x, aB[1] + bv.y,
                                               aB[2] + bv.z, aB[3] + bv.w);
    }
    #pragma unroll 2
    for (int ct = 0; ct < 8; ct++) {            // sigma half (cols 128..255)
        const unsigned short* wph = Wh + ((128 + ct * 16 + lrow) * 128) + lk8;
        const unsigned short* wpl = Wl + ((128 + ct * 16 + lrow) * 128) + lk8;
        bf16x8 wh[4], wl[4];
        #pragma unroll
        for (int ki = 0; ki < 4; ki++) {
            wh[ki] = *(const bf16x8*)(wph + ki * 32);
            wl[ki] = *(const bf16x8*)(wpl + ki * 32);
        }
        f32x4 aA = {}, aB = {};
        #pragma unroll
        for (int ki = 0; ki < 4; ki++) {
            aA = MFMA16(wh[ki], b0[ki], aA);
            aB = MFMA16(wh[ki], b1[ki], aB);
            aA = MFMA16(wl[ki], b0[ki], aA);
            aB = MFMA16(wl[ki], b1[ki], aB);
        }
        int f0 = ct * 16 + fq;
        float4 bv = *(const float4*)(bsig + f0);
        float tA[4], tB[4];
        #pragma unroll
        for (int q = 0; q < 4; q++) {
            float xa = aA[q] + ((const float*)&bv)[q];
            tA[q] = fmaxf(xa, 0.f) + log1pf(expf(-fabsf(xa))) + 1e-7f;
            float xb = aB[q] + ((const float*)&bv)[q];
            tB[q] = fmaxf(xb, 0.f) + log1pf(expf(-fabsf(xb))) + 1e-7f;
        }
        *(float4*)(sg0 + f0 * 4) = make_float4(tA[0], tA[1], tA[2], tA[3]);
        *(float4*)(sg1 + f0 * 4) = make_float4(tB[0], tB[1], tB[2], tB[3]);
    }
}

// ---------------- launch ----------------

extern "C" void kernel_launch(void* const* d_in, const int* in_sizes, int n_in,
                              void* d_out, int out_size, void* d_ws, size_t ws_size,
                              hipStream_t stream) {
    const float* x    = (const float*)d_in[0];
    const int*   ei   = (const int*)d_in[1];
    const int*   row  = ei;
    const int*   col  = ei + N_EDGES;
    const float* W0   = (const float*)d_in[2];
    const float* b0   = (const float*)d_in[3];
    const float* Wmu  = (const float*)d_in[4];
    const float* bmu  = (const float*)d_in[5];
    const float* Wsig = (const float*)d_in[6];
    const float* bsig = (const float*)d_in[7];
    char* outc = (char*)d_out;

    unsigned short* W0h  = (unsigned short*)d_ws;       // 128*256
    unsigned short* W0l  = W0h + 32768;
    unsigned short* Wmsh = W0l + 32768;                 // 256*128
    unsigned short* Wmsl = Wmsh + 32768;
    int*   cnt       = (int*)(Wmsl + 32768);
    int*   gcur      = cnt + N_NODES;                   // NBKT ints (memset)
    int*   bktBase   = gcur + NBKT;                     // NBKT ints
    int*   offs      = bktBase + NBKT;
    float* dinvp     = (float*)(offs + N_NODES);
    int*   sortedRow = (int*)(dinvp + N_NODES);

    u64* entries = (u64*)(outc + HALFB);                // sigma half scratch

    hipMemsetAsync(gcur, 0, NBKT * sizeof(int), stream);
    prep_w<<<384, 256, 0, stream>>>(W0, Wmu, Wsig, W0h, W0l, Wmsh, Wmsl);
    bin_kernel<<<(N_EDGES + EPB - 1) / EPB, 256, 0, stream>>>(row, col, gcur, entries);
    bktscan_kernel<<<1, 256, 0, stream>>>(gcur, bktBase);
    csr_kernel<<<NBKT, 256, 0, stream>>>(entries, gcur, bktBase, cnt, offs, dinvp, sortedRow);

    gemm1_mfma<<<(N_NODES / 32 + 1) / 2, 128, 0, stream>>>(x, W0h, W0l, outc);
    agg_bf16<1><<<N_NODES / 4, 256, 0, stream>>>(outc + 256, outc + HALFB,
                                                 offs, cnt, sortedRow, dinvp, b0);
    agg_bf16<0><<<N_NODES / 4, 256, 0, stream>>>(outc + HALFB, outc,
                                                 offs, cnt, sortedRow, dinvp, nullptr);
    gemm2_mfma<<<(N_NODES / 32 + 1) / 2, 128, 0, stream>>>(Wmsh, Wmsl, bmu, bsig, outc);
}

// Round 10
// 335.703 us; speedup vs baseline: 1.1143x; 1.1143x over previous
//
#include <hip/hip_runtime.h>
#include <math.h>

#define N_NODES 100000
#define N_EDGES 1600000
#define ROWB    512                 // bytes per row slot in d_out
#define HALFB   51200000ull         // byte offset of second output (sigma half)
#define NBKT    196                 // sort buckets (512 dst nodes each)
#define BSH     9
#define BCAP    10240               // entries per bucket (mean 8192, >20 sigma margin)
#define EPB     1024                // edges per bin block

typedef float  f32x4  __attribute__((ext_vector_type(4)));
typedef __bf16 bf16x8 __attribute__((ext_vector_type(8)));
typedef short  s16x8  __attribute__((ext_vector_type(8)));
typedef unsigned long long u64;

__device__ __forceinline__ unsigned short f2bf(float f) {
    unsigned int u = __builtin_bit_cast(unsigned int, f);
    u += 0x7FFFu + ((u >> 16) & 1u);          // RNE
    return (unsigned short)(u >> 16);
}
__device__ __forceinline__ float bf2f(unsigned short h) {
    unsigned int u = ((unsigned int)h) << 16;
    return __builtin_bit_cast(float, u);
}
__device__ __forceinline__ float bf_lo(unsigned int u) {
    return __builtin_bit_cast(float, u << 16);
}
__device__ __forceinline__ float bf_hi(unsigned int u) {
    return __builtin_bit_cast(float, u & 0xFFFF0000u);
}
__device__ __forceinline__ bf16x8 packhi(const float4& a, const float4& b) {
    float v[8] = {a.x, a.y, a.z, a.w, b.x, b.y, b.z, b.w};
    s16x8 hh;
    #pragma unroll
    for (int j = 0; j < 8; j++) hh[j] = (short)f2bf(v[j]);
    return __builtin_bit_cast(bf16x8, hh);
}

#define MFMA16(a, b, c) __builtin_amdgcn_mfma_f32_16x16x32_bf16((a), (b), (c), 0, 0, 0)

// ---------------- sort pass B: bucket-binning ----------------

__launch_bounds__(256)
__global__ void bin_kernel(const int* __restrict__ row, const int* __restrict__ col,
                           int* __restrict__ gcur, u64* __restrict__ entries) {
    __shared__ int hist[NBKT], base[NBKT], cur[NBKT];
    const int tid = threadIdx.x;
    for (int i = tid; i < NBKT; i += 256) { hist[i] = 0; cur[i] = 0; }
    __syncthreads();
    const int e0 = blockIdx.x * EPB;
    int cols[4];
    #pragma unroll
    for (int it = 0; it < 4; it++) {
        int e = e0 + it * 256 + tid;
        int c = (e < N_EDGES) ? col[e] : -1;
        cols[it] = c;
        if (c >= 0) atomicAdd(&hist[c >> BSH], 1);
    }
    __syncthreads();
    for (int i = tid; i < NBKT; i += 256)
        base[i] = atomicAdd(&gcur[i], hist[i]);
    __syncthreads();
    #pragma unroll
    for (int it = 0; it < 4; it++) {
        int e = e0 + it * 256 + tid;
        int c = cols[it];
        if (c >= 0) {
            int b = c >> BSH;
            int r = atomicAdd(&cur[b], 1);
            entries[(size_t)b * BCAP + base[b] + r] =
                ((u64)(unsigned)c << 32) | (unsigned)row[e];
        }
    }
}

// ---------------- bucket-base scan (196 values, 1 block) ----------------

__global__ void bktscan_kernel(const int* __restrict__ gcur, int* __restrict__ bktBase) {
    __shared__ int s[256];
    const int tid = threadIdx.x;
    int v = (tid < NBKT) ? gcur[tid] : 0;
    s[tid] = v;
    __syncthreads();
    for (int d = 1; d < 256; d <<= 1) {
        int t = (tid >= d) ? s[tid - d] : 0;
        __syncthreads();
        s[tid] += t;
        __syncthreads();
    }
    if (tid < NBKT) bktBase[tid] = s[tid] - v;
}

// ---------------- sort pass C: per-bucket histogram + scan + scatter ----------------

__launch_bounds__(256)
__global__ void csr_kernel(const u64* __restrict__ entries, const int* __restrict__ gcur,
                           const int* __restrict__ bktBase,
                           int* __restrict__ cnt, int* __restrict__ offs,
                           float* __restrict__ dinv, int* __restrict__ sortedRow) {
    __shared__ int lcnt[512], sA[512], sB[512], lcur[512];
    const int b = blockIdx.x, tid = threadIdx.x;
    const int n0 = b << BSH;
    lcnt[tid] = 0; lcnt[tid + 256] = 0;
    __syncthreads();
    const int nb = gcur[b], base = bktBase[b];
    const u64* ep = entries + (size_t)b * BCAP;
    for (int i = tid; i < nb; i += 256)
        atomicAdd(&lcnt[(int)(ep[i] >> 32) - n0], 1);
    __syncthreads();
    sA[tid] = lcnt[tid]; sA[tid + 256] = lcnt[tid + 256];
    __syncthreads();
    int* src = sA; int* dst = sB;
    for (int d = 1; d < 512; d <<= 1) {
        #pragma unroll
        for (int k = tid; k < 512; k += 256)
            dst[k] = src[k] + ((k >= d) ? src[k - d] : 0);
        __syncthreads();
        int* t = src; src = dst; dst = t;
    }
    #pragma unroll
    for (int k = tid; k < 512; k += 256) {
        int excl = src[k] - lcnt[k];
        lcur[k] = excl;
        int node = n0 + k;
        if (node < N_NODES) {
            offs[node] = base + excl;
            cnt[node]  = lcnt[k];
            dinv[node] = rsqrtf((float)(lcnt[k] + 1));   // +1 self loop
        }
    }
    __syncthreads();
    for (int i = tid; i < nb; i += 256) {
        u64 pk = ep[i];
        int local = (int)(pk >> 32) - n0;
        int p = base + atomicAdd(&lcur[local], 1);
        sortedRow[p] = (int)(pk & 0xFFFFFFFFu);
    }
}

// ---------------- weight pre-transpose ----------------

__global__ void prep_w(const float* __restrict__ W0, const float* __restrict__ Wmu,
                       const float* __restrict__ Wsig,
                       unsigned short* __restrict__ W0h, unsigned short* __restrict__ W0l,
                       unsigned short* __restrict__ Wmsh, unsigned short* __restrict__ Wmsl) {
    int c = blockIdx.x;
    int k = threadIdx.x;
    if (c < 128) {                               // W0 [256][128] -> [128 cols][256 k]
        float v = W0[k * 128 + c];
        unsigned short h = f2bf(v);
        W0h[c * 256 + k] = h;
        W0l[c * 256 + k] = f2bf(v - bf2f(h));
    } else if (k < 128) {                        // Wmu|Wsig -> [256 cols][128 k]
        int c2 = c - 128;
        float v = (c2 < 128) ? Wmu[k * 128 + c2] : Wsig[k * 128 + (c2 - 128)];
        unsigned short h = f2bf(v);
        Wmsh[c2 * 128 + k] = h;
        Wmsl[c2 * 128 + k] = f2bf(v - bf2f(h));
    }
}

// ---------------- GEMM1: t0_bf16 = x @ W0 (2-term W comp, A=W, B-stationary) -----------
// Block = 2 waves; wave owns 64 nodes, x rows packed to bf16 in regs (read once).
// W chunks (16 cols x 256 k x hi/lo = 16KB) staged per ct via double-buffered LDS,
// shared by both waves -> weight global traffic ~100MB total. 1 barrier per ct.

__launch_bounds__(128)
__global__ void gemm1_mfma(const float* __restrict__ x,
                           const unsigned short* __restrict__ Wh,
                           const unsigned short* __restrict__ Wl,
                           char* __restrict__ outc) {
    __shared__ __align__(16) char Ws[2][16384];  // [buf][hl][16col][256k] swizzled
    const int tid = threadIdx.x;
    const int wave = tid >> 6, lane = tid & 63;
    const int lrow = lane & 15, q4 = lane >> 4;
    const int swz = (lrow & 7) << 4;
    const int n0 = blockIdx.x * 128 + wave * 64;

    // upfront: pack wave's 64 x-rows to bf16 regs (B operand, full K=256)
    bf16x8 b[4][8];
    int nodes[4];
    #pragma unroll
    for (int g = 0; g < 4; g++) {
        int node = n0 + g * 16 + lrow;
        nodes[g] = node;
        int nc = node > N_NODES - 1 ? N_NODES - 1 : node;
        const float* xp = x + (size_t)nc * 256 + q4 * 8;
        #pragma unroll
        for (int ks = 0; ks < 8; ks++) {
            float4 p0 = *(const float4*)(xp + ks * 32);
            float4 p1 = *(const float4*)(xp + ks * 32 + 4);
            b[g][ks] = packhi(p0, p1);
        }
    }

    // staging map: unit u = tid + 128*j (j 0..7); hl=u>>9, col=(u>>5)&15, k8=(u&31)*8
    int sgo[8], slo[8];
    #pragma unroll
    for (int j = 0; j < 8; j++) {
        int u = tid + 128 * j;
        int col = (u >> 5) & 15, k8 = (u & 31) * 8;
        sgo[j] = col * 256 + k8;                 // elem offset within [col][k] panel
        slo[j] = (j >= 4 ? 8192 : 0) + ((col * 512 + k8 * 2) ^ ((col & 7) << 4));
    }

    // stage ct 0
    {
        int4 sw[8];
        #pragma unroll
        for (int j = 0; j < 8; j++)
            sw[j] = *(const int4*)((j >= 4 ? Wl : Wh) + sgo[j]);
        #pragma unroll
        for (int j = 0; j < 8; j++)
            *(int4*)(Ws[0] + slo[j]) = sw[j];
    }
    __syncthreads();

    #pragma unroll
    for (int ct = 0; ct < 8; ct++) {
        int4 sw[8];
        if (ct < 7) {
            #pragma unroll
            for (int j = 0; j < 8; j++)
                sw[j] = *(const int4*)((j >= 4 ? Wl : Wh) + (ct + 1) * 16 * 256 + sgo[j]);
        }
        const char* bufp = Ws[ct & 1];
        f32x4 acc[4] = {};
        #pragma unroll
        for (int hl = 0; hl < 2; hl++) {
            bf16x8 w[8];
            #pragma unroll
            for (int ks = 0; ks < 8; ks++)
                w[ks] = *(const bf16x8*)(bufp + hl * 8192 +
                        ((lrow * 512 + ks * 64 + q4 * 16) ^ swz));
            #pragma unroll
            for (int g = 0; g < 4; g++)
                #pragma unroll
                for (int ks = 0; ks < 8; ks++)
                    acc[g] = MFMA16(w[ks], b[g][ks], acc[g]);
        }
        // epilogue: t0 bf16 at mu slot +256
        const int f0 = ct * 16 + q4 * 4;
        #pragma unroll
        for (int g = 0; g < 4; g++) {
            if (nodes[g] < N_NODES) {
                ushort4 p = make_ushort4(f2bf(acc[g][0]), f2bf(acc[g][1]),
                                         f2bf(acc[g][2]), f2bf(acc[g][3]));
                *(ushort4*)(outc + (size_t)nodes[g] * ROWB + 256 + f0 * 2) = p;
            }
        }
        if (ct < 7) {
            #pragma unroll
            for (int j = 0; j < 8; j++)
                *(int4*)(Ws[(ct + 1) & 1] + slo[j]) = sw[j];
            __syncthreads();
        }
    }
}

// ---------------- aggregation: scalarized edge processing ------------------------------

template <int EPI>
__launch_bounds__(256)
__global__ void agg_bf16(const char* __restrict__ srcBase, char* __restrict__ dstBase,
                         const int* __restrict__ offs, const int* __restrict__ cnt,
                         const int* __restrict__ sortedRow, const float* __restrict__ dinv,
                         const float* __restrict__ bias) {
    const int n = blockIdx.x * 4 + (threadIdx.x >> 6);
    const int lane = threadIdx.x & 63;
    const int laneB = lane * 4;
    const float dn = dinv[n];
    unsigned int u = *(const unsigned int*)(srcBase + (size_t)n * ROWB + laneB);
    const float ws = dn * dn;
    float acc0 = ws * bf_lo(u);
    float acc1 = ws * bf_hi(u);
    const int start = __builtin_amdgcn_readfirstlane(offs[n]);
    const int num   = __builtin_amdgcn_readfirstlane(cnt[n]);

    int i = 0;
    for (; i + 8 <= num; i += 8) {
        int myr = sortedRow[start + i + (lane & 7)];
        int rs[8];
        #pragma unroll
        for (int j = 0; j < 8; j++) rs[j] = __builtin_amdgcn_readlane(myr, j);
        unsigned int ue[8];
        #pragma unroll
        for (int j = 0; j < 8; j++) {
            const char* p = srcBase + ((size_t)rs[j] << 9);   // SGPR base
            ue[j] = *(const unsigned int*)(p + laneB);
        }
        float w[8];
        #pragma unroll
        for (int j = 0; j < 8; j++) w[j] = dn * dinv[rs[j]];
        #pragma unroll
        for (int j = 0; j < 8; j++) {
            acc0 = fmaf(w[j], bf_lo(ue[j]), acc0);
            acc1 = fmaf(w[j], bf_hi(ue[j]), acc1);
        }
    }
    for (; i < num; i++) {
        int rsv = __builtin_amdgcn_readfirstlane(sortedRow[start + i]);
        const char* p = srcBase + ((size_t)rsv << 9);
        unsigned int ue = *(const unsigned int*)(p + laneB);
        float w = dn * dinv[rsv];
        acc0 = fmaf(w, bf_lo(ue), acc0);
        acc1 = fmaf(w, bf_hi(ue), acc1);
    }

    if (EPI) {
        acc0 = fmaxf(acc0 + bias[2 * lane], 0.f);
        acc1 = fmaxf(acc1 + bias[2 * lane + 1], 0.f);
    }
    unsigned int o = (unsigned int)f2bf(acc0) | ((unsigned int)f2bf(acc1) << 16);
    *(unsigned int*)(dstBase + (size_t)n * ROWB + laneB) = o;
}

// ---------------- GEMM2: [mu|sigma] = t2 @ [Wmu|Wsig] (2-term, B-stationary) -----------
// Wave owns 64 nodes; t2 rows fully in regs BEFORE any store (in-place safe, node
// partition across waves). 16 ct chunks (16 cols x 128 k x hi/lo = 8KB) via dbuf LDS.

__launch_bounds__(128)
__global__ void gemm2_mfma(const unsigned short* __restrict__ Wh,
                           const unsigned short* __restrict__ Wl,
                           const float* __restrict__ bmu, const float* __restrict__ bsig,
                           char* __restrict__ outc) {
    __shared__ __align__(16) char Ws[2][8192];   // [buf][hl][16col][128k] swizzled
    const int tid = threadIdx.x;
    const int wave = tid >> 6, lane = tid & 63;
    const int lrow = lane & 15, q4 = lane >> 4;
    const int swz = (lrow & 7) << 4;
    const int n0 = blockIdx.x * 128 + wave * 64;

    // upfront: wave's 64 t2 rows fully in regs
    bf16x8 b[4][4];
    int nodes[4];
    #pragma unroll
    for (int g = 0; g < 4; g++) {
        int node = n0 + g * 16 + lrow;
        nodes[g] = node;
        int nc = node > N_NODES - 1 ? N_NODES - 1 : node;
        const char* ap = outc + (size_t)nc * ROWB + q4 * 16;
        #pragma unroll
        for (int ki = 0; ki < 4; ki++)
            b[g][ki] = *(const bf16x8*)(ap + ki * 64);
    }

    // staging map: unit u = tid + 128*j (j 0..3); hl=j>>1, col=(u>>4)&15, k8=(u&15)*8
    int sgo[4], slo[4];
    #pragma unroll
    for (int j = 0; j < 4; j++) {
        int u = tid + 128 * j;
        int col = (u >> 4) & 15, k8 = (u & 15) * 8;
        sgo[j] = col * 128 + k8;
        slo[j] = (j >= 2 ? 4096 : 0) + ((col * 256 + k8 * 2) ^ ((col & 7) << 4));
    }

    {
        int4 sw[4];
        #pragma unroll
        for (int j = 0; j < 4; j++)
            sw[j] = *(const int4*)((j >= 2 ? Wl : Wh) + sgo[j]);
        #pragma unroll
        for (int j = 0; j < 4; j++)
            *(int4*)(Ws[0] + slo[j]) = sw[j];
    }
    __syncthreads();

    #pragma unroll
    for (int ct = 0; ct < 16; ct++) {
        int4 sw[4];
        if (ct < 15) {
            #pragma unroll
            for (int j = 0; j < 4; j++)
                sw[j] = *(const int4*)((j >= 2 ? Wl : Wh) + (ct + 1) * 16 * 128 + sgo[j]);
        }
        const char* bufp = Ws[ct & 1];
        f32x4 acc[4] = {};
        #pragma unroll
        for (int hl = 0; hl < 2; hl++) {
            bf16x8 w[4];
            #pragma unroll
            for (int ki = 0; ki < 4; ki++)
                w[ki] = *(const bf16x8*)(bufp + hl * 4096 +
                        ((lrow * 256 + ki * 64 + q4 * 16) ^ swz));
            #pragma unroll
            for (int g = 0; g < 4; g++)
                #pragma unroll
                for (int ki = 0; ki < 4; ki++)
                    acc[g] = MFMA16(w[ki], b[g][ki], acc[g]);
        }
        const int f0 = (ct & 7) * 16 + q4 * 4;
        if (ct < 8) {                            // mu cols
            float4 bv = *(const float4*)(bmu + f0);
            #pragma unroll
            for (int g = 0; g < 4; g++) {
                if (nodes[g] < N_NODES) {
                    *(float4*)(outc + (size_t)nodes[g] * ROWB + f0 * 4) =
                        make_float4(acc[g][0] + bv.x, acc[g][1] + bv.y,
                                    acc[g][2] + bv.z, acc[g][3] + bv.w);
                }
            }
        } else {                                 // sigma cols (softplus)
            float4 bv = *(const float4*)(bsig + f0);
            #pragma unroll
            for (int g = 0; g < 4; g++) {
                if (nodes[g] < N_NODES) {
                    float t[4];
                    #pragma unroll
                    for (int q = 0; q < 4; q++) {
                        float xv = acc[g][q] + ((const float*)&bv)[q];
                        t[q] = fmaxf(xv, 0.f) + log1pf(expf(-fabsf(xv))) + 1e-7f;
                    }
                    *(float4*)(outc + HALFB + (size_t)nodes[g] * ROWB + f0 * 4) =
                        make_float4(t[0], t[1], t[2], t[3]);
                }
            }
        }
        if (ct < 15) {
            #pragma unroll
            for (int j = 0; j < 4; j++)
                *(int4*)(Ws[(ct + 1) & 1] + slo[j]) = sw[j];
            __syncthreads();
        }
    }
}

// ---------------- launch ----------------

extern "C" void kernel_launch(void* const* d_in, const int* in_sizes, int n_in,
                              void* d_out, int out_size, void* d_ws, size_t ws_size,
                              hipStream_t stream) {
    const float* x    = (const float*)d_in[0];
    const int*   ei   = (const int*)d_in[1];
    const int*   row  = ei;
    const int*   col  = ei + N_EDGES;
    const float* W0   = (const float*)d_in[2];
    const float* b0   = (const float*)d_in[3];
    const float* Wmu  = (const float*)d_in[4];
    const float* bmu  = (const float*)d_in[5];
    const float* Wsig = (const float*)d_in[6];
    const float* bsig = (const float*)d_in[7];
    char* outc = (char*)d_out;

    unsigned short* W0h  = (unsigned short*)d_ws;       // 128*256
    unsigned short* W0l  = W0h + 32768;
    unsigned short* Wmsh = W0l + 32768;                 // 256*128
    unsigned short* Wmsl = Wmsh + 32768;
    int*   cnt       = (int*)(Wmsl + 32768);
    int*   gcur      = cnt + N_NODES;                   // NBKT ints (memset)
    int*   bktBase   = gcur + NBKT;                     // NBKT ints
    int*   offs      = bktBase + NBKT;
    float* dinvp     = (float*)(offs + N_NODES);
    int*   sortedRow = (int*)(dinvp + N_NODES);

    u64* entries = (u64*)(outc + HALFB);                // sigma half scratch

    hipMemsetAsync(gcur, 0, NBKT * sizeof(int), stream);
    prep_w<<<384, 256, 0, stream>>>(W0, Wmu, Wsig, W0h, W0l, Wmsh, Wmsl);
    bin_kernel<<<(N_EDGES + EPB - 1) / EPB, 256, 0, stream>>>(row, col, gcur, entries);
    bktscan_kernel<<<1, 256, 0, stream>>>(gcur, bktBase);
    csr_kernel<<<NBKT, 256, 0, stream>>>(entries, gcur, bktBase, cnt, offs, dinvp, sortedRow);

    gemm1_mfma<<<(N_NODES + 127) / 128, 128, 0, stream>>>(x, W0h, W0l, outc);
    agg_bf16<1><<<N_NODES / 4, 256, 0, stream>>>(outc + 256, outc + HALFB,
                                                 offs, cnt, sortedRow, dinvp, b0);
    agg_bf16<0><<<N_NODES / 4, 256, 0, stream>>>(outc + HALFB, outc,
                                                 offs, cnt, sortedRow, dinvp, nullptr);
    gemm2_mfma<<<(N_NODES + 127) / 128, 128, 0, stream>>>(Wmsh, Wmsl, bmu, bsig, outc);
}

// Round 11
// 319.286 us; speedup vs baseline: 1.1716x; 1.0514x over previous
//
#include <hip/hip_runtime.h>
#include <math.h>

#define N_NODES 100000
#define N_EDGES 1600000
#define ROWB    512                 // bytes per row slot in d_out
#define HALFB   51200000ull         // byte offset of second output (sigma half)
#define NBKT    196                 // sort buckets (512 dst nodes each)
#define BSH     9
#define BCAP    10240               // entries per bucket (mean 8192, >20 sigma margin)
#define EPB     1024                // edges per bin block

typedef float  f32x4  __attribute__((ext_vector_type(4)));
typedef __bf16 bf16x8 __attribute__((ext_vector_type(8)));
typedef short  s16x8  __attribute__((ext_vector_type(8)));
typedef unsigned long long u64;

__device__ __forceinline__ unsigned short f2bf(float f) {
    unsigned int u = __builtin_bit_cast(unsigned int, f);
    u += 0x7FFFu + ((u >> 16) & 1u);          // RNE
    return (unsigned short)(u >> 16);
}
__device__ __forceinline__ float bf2f(unsigned short h) {
    unsigned int u = ((unsigned int)h) << 16;
    return __builtin_bit_cast(float, u);
}
__device__ __forceinline__ float bf_lo(unsigned int u) {
    return __builtin_bit_cast(float, u << 16);
}
__device__ __forceinline__ float bf_hi(unsigned int u) {
    return __builtin_bit_cast(float, u & 0xFFFF0000u);
}
__device__ __forceinline__ bf16x8 packhi(const float4& a, const float4& b) {
    float v[8] = {a.x, a.y, a.z, a.w, b.x, b.y, b.z, b.w};
    s16x8 hh;
    #pragma unroll
    for (int j = 0; j < 8; j++) hh[j] = (short)f2bf(v[j]);
    return __builtin_bit_cast(bf16x8, hh);
}

#define MFMA16(a, b, c) __builtin_amdgcn_mfma_f32_16x16x32_bf16((a), (b), (c), 0, 0, 0)

// ---------------- sort pass B: bucket-binning ----------------

__launch_bounds__(256)
__global__ void bin_kernel(const int* __restrict__ row, const int* __restrict__ col,
                           int* __restrict__ gcur, u64* __restrict__ entries) {
    __shared__ int hist[NBKT], base[NBKT], cur[NBKT];
    const int tid = threadIdx.x;
    for (int i = tid; i < NBKT; i += 256) { hist[i] = 0; cur[i] = 0; }
    __syncthreads();
    const int e0 = blockIdx.x * EPB;
    int cols[4];
    #pragma unroll
    for (int it = 0; it < 4; it++) {
        int e = e0 + it * 256 + tid;
        int c = (e < N_EDGES) ? col[e] : -1;
        cols[it] = c;
        if (c >= 0) atomicAdd(&hist[c >> BSH], 1);
    }
    __syncthreads();
    for (int i = tid; i < NBKT; i += 256)
        base[i] = atomicAdd(&gcur[i], hist[i]);
    __syncthreads();
    #pragma unroll
    for (int it = 0; it < 4; it++) {
        int e = e0 + it * 256 + tid;
        int c = cols[it];
        if (c >= 0) {
            int b = c >> BSH;
            int r = atomicAdd(&cur[b], 1);
            entries[(size_t)b * BCAP + base[b] + r] =
                ((u64)(unsigned)c << 32) | (unsigned)row[e];
        }
    }
}

// ---------------- bucket-base scan (196 values, 1 block) ----------------

__global__ void bktscan_kernel(const int* __restrict__ gcur, int* __restrict__ bktBase) {
    __shared__ int s[256];
    const int tid = threadIdx.x;
    int v = (tid < NBKT) ? gcur[tid] : 0;
    s[tid] = v;
    __syncthreads();
    for (int d = 1; d < 256; d <<= 1) {
        int t = (tid >= d) ? s[tid - d] : 0;
        __syncthreads();
        s[tid] += t;
        __syncthreads();
    }
    if (tid < NBKT) bktBase[tid] = s[tid] - v;
}

// ---------------- sort pass C: per-bucket histogram + scan + scatter ----------------

__launch_bounds__(256)
__global__ void csr_kernel(const u64* __restrict__ entries, const int* __restrict__ gcur,
                           const int* __restrict__ bktBase,
                           int* __restrict__ cnt, int* __restrict__ offs,
                           float* __restrict__ dinv, int* __restrict__ sortedRow) {
    __shared__ int lcnt[512], sA[512], sB[512], lcur[512];
    const int b = blockIdx.x, tid = threadIdx.x;
    const int n0 = b << BSH;
    lcnt[tid] = 0; lcnt[tid + 256] = 0;
    __syncthreads();
    const int nb = gcur[b], base = bktBase[b];
    const u64* ep = entries + (size_t)b * BCAP;
    for (int i = tid; i < nb; i += 256)
        atomicAdd(&lcnt[(int)(ep[i] >> 32) - n0], 1);
    __syncthreads();
    sA[tid] = lcnt[tid]; sA[tid + 256] = lcnt[tid + 256];
    __syncthreads();
    int* src = sA; int* dst = sB;
    for (int d = 1; d < 512; d <<= 1) {
        #pragma unroll
        for (int k = tid; k < 512; k += 256)
            dst[k] = src[k] + ((k >= d) ? src[k - d] : 0);
        __syncthreads();
        int* t = src; src = dst; dst = t;
    }
    #pragma unroll
    for (int k = tid; k < 512; k += 256) {
        int excl = src[k] - lcnt[k];
        lcur[k] = excl;
        int node = n0 + k;
        if (node < N_NODES) {
            offs[node] = base + excl;
            cnt[node]  = lcnt[k];
            dinv[node] = rsqrtf((float)(lcnt[k] + 1));   // +1 self loop
        }
    }
    __syncthreads();
    for (int i = tid; i < nb; i += 256) {
        u64 pk = ep[i];
        int local = (int)(pk >> 32) - n0;
        int p = base + atomicAdd(&lcur[local], 1);
        sortedRow[p] = (int)(pk & 0xFFFFFFFFu);
    }
}

// ---------------- weight pre-transpose ----------------

__global__ void prep_w(const float* __restrict__ W0, const float* __restrict__ Wmu,
                       const float* __restrict__ Wsig,
                       unsigned short* __restrict__ W0h, unsigned short* __restrict__ W0l,
                       unsigned short* __restrict__ Wmsh, unsigned short* __restrict__ Wmsl) {
    int c = blockIdx.x;
    int k = threadIdx.x;
    if (c < 128) {                               // W0 [256][128] -> [128 cols][256 k]
        float v = W0[k * 128 + c];
        unsigned short h = f2bf(v);
        W0h[c * 256 + k] = h;
        W0l[c * 256 + k] = f2bf(v - bf2f(h));
    } else if (k < 128) {                        // Wmu|Wsig -> [256 cols][128 k]
        int c2 = c - 128;
        float v = (c2 < 128) ? Wmu[k * 128 + c2] : Wsig[k * 128 + (c2 - 128)];
        unsigned short h = f2bf(v);
        Wmsh[c2 * 128 + k] = h;
        Wmsl[c2 * 128 + k] = f2bf(v - bf2f(h));
    }
}

// ---------------- GEMM1: t0_bf16 = x @ W0 (2-term W comp, A=W, seq-flush) -------------
// 256 thr = 4 waves x 32 nodes (128 nodes/block). W ct-chunks (16 cols x 256k x hi/lo
// = 16KB) double-buffered; t0 accumulated into 32KB LDS out-buffer, flushed as
// 256B-per-node contiguous bursts at the end.

__launch_bounds__(256, 2)
__global__ void gemm1_mfma(const float* __restrict__ x,
                           const unsigned short* __restrict__ Wh,
                           const unsigned short* __restrict__ Wl,
                           char* __restrict__ outc) {
    __shared__ __align__(16) char L[65536];      // [0,32K): W dbuf; [32K,64K): t0 out
    const int tid = threadIdx.x;
    const int wave = tid >> 6, lane = tid & 63;
    const int lrow = lane & 15, q4 = lane >> 4;
    const int swz = (lrow & 7) << 4;
    const int n0 = blockIdx.x * 128;

    // B operand: wave's 32 x-rows packed to bf16 regs (read once, K=256)
    bf16x8 b[2][8];
    int nodes[2];
    #pragma unroll
    for (int g = 0; g < 2; g++) {
        int node = n0 + wave * 32 + g * 16 + lrow;
        nodes[g] = node;
        int nc = node > N_NODES - 1 ? N_NODES - 1 : node;
        const float* xp = x + (size_t)nc * 256 + q4 * 8;
        #pragma unroll
        for (int ks = 0; ks < 8; ks++) {
            float4 p0 = *(const float4*)(xp + ks * 32);
            float4 p1 = *(const float4*)(xp + ks * 32 + 4);
            b[g][ks] = packhi(p0, p1);
        }
    }

    // staging map: 1024x16B units; u = tid + 256j; hl=u>>9, col=(u>>5)&15, k8=(u&31)*8
    int sgo[4], slo[4];
    #pragma unroll
    for (int j = 0; j < 4; j++) {
        int u = tid + 256 * j;
        int col = (u >> 5) & 15, k8 = (u & 31) * 8;
        sgo[j] = col * 256 + k8;
        slo[j] = (j >= 2 ? 8192 : 0) + ((col * 512 + k8 * 2) ^ ((col & 7) << 4));
    }

    {   // stage ct 0
        int4 sw[4];
        #pragma unroll
        for (int j = 0; j < 4; j++)
            sw[j] = *(const int4*)((j >= 2 ? Wl : Wh) + sgo[j]);
        #pragma unroll
        for (int j = 0; j < 4; j++)
            *(int4*)(L + slo[j]) = sw[j];
    }
    __syncthreads();

    #pragma unroll
    for (int ct = 0; ct < 8; ct++) {
        int4 sw[4];
        if (ct < 7) {
            #pragma unroll
            for (int j = 0; j < 4; j++)
                sw[j] = *(const int4*)((j >= 2 ? Wl : Wh) + (ct + 1) * 16 * 256 + sgo[j]);
        }
        const char* bufp = L + (ct & 1) * 16384;
        f32x4 acc[2] = {};
        #pragma unroll
        for (int hl = 0; hl < 2; hl++) {
            bf16x8 w[8];
            #pragma unroll
            for (int ks = 0; ks < 8; ks++)
                w[ks] = *(const bf16x8*)(bufp + hl * 8192 +
                        ((lrow * 512 + ks * 64 + q4 * 16) ^ swz));
            #pragma unroll
            for (int g = 0; g < 2; g++)
                #pragma unroll
                for (int ks = 0; ks < 8; ks++)
                    acc[g] = MFMA16(w[ks], b[g][ks], acc[g]);
        }
        // acc -> t0 out-buffer (bf16, swizzled)
        #pragma unroll
        for (int g = 0; g < 2; g++) {
            int node_l = wave * 32 + g * 16 + lrow;
            int a = (node_l * 256 + ct * 32 + q4 * 8) ^ ((node_l & 7) << 4);
            ushort4 p = make_ushort4(f2bf(acc[g][0]), f2bf(acc[g][1]),
                                     f2bf(acc[g][2]), f2bf(acc[g][3]));
            *(ushort4*)(L + 32768 + a) = p;
        }
        if (ct < 7) {
            #pragma unroll
            for (int j = 0; j < 4; j++)
                *(int4*)(L + (((ct + 1) & 1) * 16384) + slo[j]) = sw[j];
            __syncthreads();
        }
    }
    __syncthreads();
    // flush t0: 32KB, 256B per node at slot +256
    #pragma unroll
    for (int it = 0; it < 8; it++) {
        int linear = it * 4096 + tid * 16;
        int node_l = linear >> 8, off = linear & 255;
        int4 v = *(const int4*)(L + 32768 + (linear ^ ((node_l & 7) << 4)));
        int node = n0 + node_l;
        if (node < N_NODES)
            *(int4*)(outc + (size_t)node * ROWB + 256 + off) = v;
    }
}

// ---------------- aggregation: scalarized edge processing ------------------------------

template <int EPI>
__launch_bounds__(256)
__global__ void agg_bf16(const char* __restrict__ srcBase, char* __restrict__ dstBase,
                         const int* __restrict__ offs, const int* __restrict__ cnt,
                         const int* __restrict__ sortedRow, const float* __restrict__ dinv,
                         const float* __restrict__ bias) {
    const int n = blockIdx.x * 4 + (threadIdx.x >> 6);
    const int lane = threadIdx.x & 63;
    const int laneB = lane * 4;
    const float dn = dinv[n];
    unsigned int u = *(const unsigned int*)(srcBase + (size_t)n * ROWB + laneB);
    const float ws = dn * dn;
    float acc0 = ws * bf_lo(u);
    float acc1 = ws * bf_hi(u);
    const int start = __builtin_amdgcn_readfirstlane(offs[n]);
    const int num   = __builtin_amdgcn_readfirstlane(cnt[n]);

    int i = 0;
    for (; i + 8 <= num; i += 8) {
        int myr = sortedRow[start + i + (lane & 7)];
        int rs[8];
        #pragma unroll
        for (int j = 0; j < 8; j++) rs[j] = __builtin_amdgcn_readlane(myr, j);
        unsigned int ue[8];
        #pragma unroll
        for (int j = 0; j < 8; j++) {
            const char* p = srcBase + ((size_t)rs[j] << 9);   // SGPR base
            ue[j] = *(const unsigned int*)(p + laneB);
        }
        float w[8];
        #pragma unroll
        for (int j = 0; j < 8; j++) w[j] = dn * dinv[rs[j]];
        #pragma unroll
        for (int j = 0; j < 8; j++) {
            acc0 = fmaf(w[j], bf_lo(ue[j]), acc0);
            acc1 = fmaf(w[j], bf_hi(ue[j]), acc1);
        }
    }
    for (; i < num; i++) {
        int rsv = __builtin_amdgcn_readfirstlane(sortedRow[start + i]);
        const char* p = srcBase + ((size_t)rsv << 9);
        unsigned int ue = *(const unsigned int*)(p + laneB);
        float w = dn * dinv[rsv];
        acc0 = fmaf(w, bf_lo(ue), acc0);
        acc1 = fmaf(w, bf_hi(ue), acc1);
    }

    if (EPI) {
        acc0 = fmaxf(acc0 + bias[2 * lane], 0.f);
        acc1 = fmaxf(acc1 + bias[2 * lane + 1], 0.f);
    }
    unsigned int o = (unsigned int)f2bf(acc0) | ((unsigned int)f2bf(acc1) << 16);
    *(unsigned int*)(dstBase + (size_t)n * ROWB + laneB) = o;
}

// ---------------- GEMM2: [mu|sigma] = t2 @ [Wmu|Wsig] (2-term, seq-flush) --------------
// 256 thr = 4 waves x 32 nodes (128 nodes/block). 16 ct chunks (16 cols x 128k x hi/lo
// = 8KB) double-buffered. Output accumulated in 64KB LDS buffer per half, flushed as
// fully contiguous 64KB streams (bias/softplus fused). All t2 reads precede barriers.

__launch_bounds__(256, 2)
__global__ void gemm2_mfma(const unsigned short* __restrict__ Wh,
                           const unsigned short* __restrict__ Wl,
                           const float* __restrict__ bmu, const float* __restrict__ bsig,
                           char* __restrict__ outc) {
    __shared__ __align__(16) char L[81920];      // [0,16K): W dbuf; [16K,80K): out half
    const int tid = threadIdx.x;
    const int wave = tid >> 6, lane = tid & 63;
    const int lrow = lane & 15, q4 = lane >> 4;
    const int swz = (lrow & 7) << 4;
    const int n0 = blockIdx.x * 128;

    // B operand: wave's 32 t2 rows fully in regs before any barrier
    bf16x8 b[2][4];
    #pragma unroll
    for (int g = 0; g < 2; g++) {
        int node = n0 + wave * 32 + g * 16 + lrow;
        int nc = node > N_NODES - 1 ? N_NODES - 1 : node;
        const char* ap = outc + (size_t)nc * ROWB + q4 * 16;
        #pragma unroll
        for (int ki = 0; ki < 4; ki++)
            b[g][ki] = *(const bf16x8*)(ap + ki * 64);
    }

    // staging map: 512x16B units; u = tid + 256j; hl=j, col=tid>>4, k8=(tid&15)*8
    const int colS = tid >> 4, k8S = (tid & 15) * 8;
    const int sgo = colS * 128 + k8S;
    const int sloc = (colS * 256 + k8S * 2) ^ ((colS & 7) << 4);

    {   // stage ct 0
        int4 h = *(const int4*)(Wh + sgo);
        int4 l = *(const int4*)(Wl + sgo);
        *(int4*)(L + sloc) = h;
        *(int4*)(L + 4096 + sloc) = l;
    }
    __syncthreads();

    #pragma unroll
    for (int ct = 0; ct < 16; ct++) {
        int4 swh, swl;
        if (ct < 15) {
            swh = *(const int4*)(Wh + (ct + 1) * 16 * 128 + sgo);
            swl = *(const int4*)(Wl + (ct + 1) * 16 * 128 + sgo);
        }
        const char* bufp = L + (ct & 1) * 8192;
        f32x4 acc[2] = {};
        #pragma unroll
        for (int hl = 0; hl < 2; hl++) {
            bf16x8 w[4];
            #pragma unroll
            for (int ki = 0; ki < 4; ki++)
                w[ki] = *(const bf16x8*)(bufp + hl * 4096 +
                        ((lrow * 256 + ki * 64 + q4 * 16) ^ swz));
            #pragma unroll
            for (int g = 0; g < 2; g++)
                #pragma unroll
                for (int ki = 0; ki < 4; ki++)
                    acc[g] = MFMA16(w[ki], b[g][ki], acc[g]);
        }
        // acc -> out-buffer (fp32, swizzled)
        const int f0 = (ct & 7) * 16 + q4 * 4;
        #pragma unroll
        for (int g = 0; g < 2; g++) {
            int node_l = wave * 32 + g * 16 + lrow;
            int a = (node_l * 512 + f0 * 4) ^ ((node_l & 7) << 4);
            *(f32x4*)(L + 16384 + a) = acc[g];
        }
        if ((ct & 7) == 7) {                     // flush this half
            __syncthreads();
            const bool isMu = (ct < 8);
            #pragma unroll
            for (int it = 0; it < 16; it++) {
                int linear = it * 4096 + tid * 16;
                int node_l = linear >> 9;
                int colf = (linear >> 2) & 127;
                f32x4 v = *(const f32x4*)(L + 16384 + (linear ^ ((node_l & 7) << 4)));
                int node = n0 + node_l;
                if (node < N_NODES) {
                    if (isMu) {
                        float4 bv = *(const float4*)(bmu + colf);
                        *(float4*)(outc + (size_t)n0 * ROWB + linear) =
                            make_float4(v[0] + bv.x, v[1] + bv.y, v[2] + bv.z, v[3] + bv.w);
                    } else {
                        float4 bv = *(const float4*)(bsig + colf);
                        float t[4];
                        #pragma unroll
                        for (int q = 0; q < 4; q++) {
                            float xv = v[q] + ((const float*)&bv)[q];
                            t[q] = fmaxf(xv, 0.f) + log1pf(expf(-fabsf(xv))) + 1e-7f;
                        }
                        *(float4*)(outc + HALFB + (size_t)n0 * ROWB + linear) =
                            make_float4(t[0], t[1], t[2], t[3]);
                    }
                }
            }
            __syncthreads();
        }
        if (ct < 15) {
            char* nb = L + ((ct + 1) & 1) * 8192;
            *(int4*)(nb + sloc) = swh;
            *(int4*)(nb + 4096 + sloc) = swl;
            __syncthreads();
        }
    }
}

// ---------------- launch ----------------

extern "C" void kernel_launch(void* const* d_in, const int* in_sizes, int n_in,
                              void* d_out, int out_size, void* d_ws, size_t ws_size,
                              hipStream_t stream) {
    const float* x    = (const float*)d_in[0];
    const int*   ei   = (const int*)d_in[1];
    const int*   row  = ei;
    const int*   col  = ei + N_EDGES;
    const float* W0   = (const float*)d_in[2];
    const float* b0   = (const float*)d_in[3];
    const float* Wmu  = (const float*)d_in[4];
    const float* bmu  = (const float*)d_in[5];
    const float* Wsig = (const float*)d_in[6];
    const float* bsig = (const float*)d_in[7];
    char* outc = (char*)d_out;

    unsigned short* W0h  = (unsigned short*)d_ws;       // 128*256
    unsigned short* W0l  = W0h + 32768;
    unsigned short* Wmsh = W0l + 32768;                 // 256*128
    unsigned short* Wmsl = Wmsh + 32768;
    int*   cnt       = (int*)(Wmsl + 32768);
    int*   gcur      = cnt + N_NODES;                   // NBKT ints (memset)
    int*   bktBase   = gcur + NBKT;                     // NBKT ints
    int*   offs      = bktBase + NBKT;
    float* dinvp     = (float*)(offs + N_NODES);
    int*   sortedRow = (int*)(dinvp + N_NODES);

    u64* entries = (u64*)(outc + HALFB);                // sigma half scratch

    hipMemsetAsync(gcur, 0, NBKT * sizeof(int), stream);
    prep_w<<<384, 256, 0, stream>>>(W0, Wmu, Wsig, W0h, W0l, Wmsh, Wmsl);
    bin_kernel<<<(N_EDGES + EPB - 1) / EPB, 256, 0, stream>>>(row, col, gcur, entries);
    bktscan_kernel<<<1, 256, 0, stream>>>(gcur, bktBase);
    csr_kernel<<<NBKT, 256, 0, stream>>>(entries, gcur, bktBase, cnt, offs, dinvp, sortedRow);

    gemm1_mfma<<<(N_NODES + 127) / 128, 256, 0, stream>>>(x, W0h, W0l, outc);
    agg_bf16<1><<<N_NODES / 4, 256, 0, stream>>>(outc + 256, outc + HALFB,
                                                 offs, cnt, sortedRow, dinvp, b0);
    agg_bf16<0><<<N_NODES / 4, 256, 0, stream>>>(outc + HALFB, outc,
                                                 offs, cnt, sortedRow, dinvp, nullptr);
    gemm2_mfma<<<(N_NODES + 127) / 128, 256, 0, stream>>>(Wmsh, Wmsl, bmu, bsig, outc);
}

// Round 12
// 311.055 us; speedup vs baseline: 1.2026x; 1.0265x over previous
//
#include <hip/hip_runtime.h>
#include <math.h>

#define N_NODES 100000
#define N_EDGES 1600000
#define ROWB    512                 // bytes per row slot in d_out (legacy layout)
#define HALFB   51200000ull         // byte offset of second output (sigma half)
#define NBKT    196                 // sort buckets (512 dst nodes each)
#define BSH     9
#define BCAP    10240               // entries per bucket (mean 8192, >20 sigma margin)
#define EPB     1024                // edges per bin block

typedef float  f32x4  __attribute__((ext_vector_type(4)));
typedef __bf16 bf16x8 __attribute__((ext_vector_type(8)));
typedef short  s16x8  __attribute__((ext_vector_type(8)));
typedef unsigned long long u64;

__device__ __forceinline__ unsigned short f2bf(float f) {
    unsigned int u = __builtin_bit_cast(unsigned int, f);
    u += 0x7FFFu + ((u >> 16) & 1u);          // RNE
    return (unsigned short)(u >> 16);
}
__device__ __forceinline__ float bf2f(unsigned short h) {
    unsigned int u = ((unsigned int)h) << 16;
    return __builtin_bit_cast(float, u);
}
__device__ __forceinline__ float bf_lo(unsigned int u) {
    return __builtin_bit_cast(float, u << 16);
}
__device__ __forceinline__ float bf_hi(unsigned int u) {
    return __builtin_bit_cast(float, u & 0xFFFF0000u);
}
__device__ __forceinline__ bf16x8 packhi(const float4& a, const float4& b) {
    float v[8] = {a.x, a.y, a.z, a.w, b.x, b.y, b.z, b.w};
    s16x8 hh;
    #pragma unroll
    for (int j = 0; j < 8; j++) hh[j] = (short)f2bf(v[j]);
    return __builtin_bit_cast(bf16x8, hh);
}
__device__ __forceinline__ void ntstore4(void* p, f32x4 v) {
    __builtin_nontemporal_store(v, (f32x4*)p);
}

#define MFMA16(a, b, c) __builtin_amdgcn_mfma_f32_16x16x32_bf16((a), (b), (c), 0, 0, 0)

// ---------------- sort pass B: bucket-binning ----------------

__launch_bounds__(256)
__global__ void bin_kernel(const int* __restrict__ row, const int* __restrict__ col,
                           int* __restrict__ gcur, u64* __restrict__ entries) {
    __shared__ int hist[NBKT], base[NBKT], cur[NBKT];
    const int tid = threadIdx.x;
    for (int i = tid; i < NBKT; i += 256) { hist[i] = 0; cur[i] = 0; }
    __syncthreads();
    const int e0 = blockIdx.x * EPB;
    int cols[4];
    #pragma unroll
    for (int it = 0; it < 4; it++) {
        int e = e0 + it * 256 + tid;
        int c = (e < N_EDGES) ? col[e] : -1;
        cols[it] = c;
        if (c >= 0) atomicAdd(&hist[c >> BSH], 1);
    }
    __syncthreads();
    for (int i = tid; i < NBKT; i += 256)
        base[i] = atomicAdd(&gcur[i], hist[i]);
    __syncthreads();
    #pragma unroll
    for (int it = 0; it < 4; it++) {
        int e = e0 + it * 256 + tid;
        int c = cols[it];
        if (c >= 0) {
            int b = c >> BSH;
            int r = atomicAdd(&cur[b], 1);
            entries[(size_t)b * BCAP + base[b] + r] =
                ((u64)(unsigned)c << 32) | (unsigned)row[e];
        }
    }
}

// ---------------- bucket-base scan (196 values, 1 block) ----------------

__global__ void bktscan_kernel(const int* __restrict__ gcur, int* __restrict__ bktBase) {
    __shared__ int s[256];
    const int tid = threadIdx.x;
    int v = (tid < NBKT) ? gcur[tid] : 0;
    s[tid] = v;
    __syncthreads();
    for (int d = 1; d < 256; d <<= 1) {
        int t = (tid >= d) ? s[tid - d] : 0;
        __syncthreads();
        s[tid] += t;
        __syncthreads();
    }
    if (tid < NBKT) bktBase[tid] = s[tid] - v;
}

// ---------------- sort pass C: per-bucket histogram + scan + scatter ----------------

__launch_bounds__(256)
__global__ void csr_kernel(const u64* __restrict__ entries, const int* __restrict__ gcur,
                           const int* __restrict__ bktBase,
                           int* __restrict__ cnt, int* __restrict__ offs,
                           float* __restrict__ dinv, int* __restrict__ sortedRow) {
    __shared__ int lcnt[512], sA[512], sB[512], lcur[512];
    const int b = blockIdx.x, tid = threadIdx.x;
    const int n0 = b << BSH;
    lcnt[tid] = 0; lcnt[tid + 256] = 0;
    __syncthreads();
    const int nb = gcur[b], base = bktBase[b];
    const u64* ep = entries + (size_t)b * BCAP;
    for (int i = tid; i < nb; i += 256)
        atomicAdd(&lcnt[(int)(ep[i] >> 32) - n0], 1);
    __syncthreads();
    sA[tid] = lcnt[tid]; sA[tid + 256] = lcnt[tid + 256];
    __syncthreads();
    int* src = sA; int* dst = sB;
    for (int d = 1; d < 512; d <<= 1) {
        #pragma unroll
        for (int k = tid; k < 512; k += 256)
            dst[k] = src[k] + ((k >= d) ? src[k - d] : 0);
        __syncthreads();
        int* t = src; src = dst; dst = t;
    }
    #pragma unroll
    for (int k = tid; k < 512; k += 256) {
        int excl = src[k] - lcnt[k];
        lcur[k] = excl;
        int node = n0 + k;
        if (node < N_NODES) {
            offs[node] = base + excl;
            cnt[node]  = lcnt[k];
            dinv[node] = rsqrtf((float)(lcnt[k] + 1));   // +1 self loop
        }
    }
    __syncthreads();
    for (int i = tid; i < nb; i += 256) {
        u64 pk = ep[i];
        int local = (int)(pk >> 32) - n0;
        int p = base + atomicAdd(&lcur[local], 1);
        sortedRow[p] = (int)(pk & 0xFFFFFFFFu);
    }
}

// ---------------- weight pre-transpose ----------------

__global__ void prep_w(const float* __restrict__ W0, const float* __restrict__ Wmu,
                       const float* __restrict__ Wsig,
                       unsigned short* __restrict__ W0h, unsigned short* __restrict__ W0l,
                       unsigned short* __restrict__ Wmsh, unsigned short* __restrict__ Wmsl) {
    int c = blockIdx.x;
    int k = threadIdx.x;
    if (c < 128) {                               // W0 [256][128] -> [128 cols][256 k]
        float v = W0[k * 128 + c];
        unsigned short h = f2bf(v);
        W0h[c * 256 + k] = h;
        W0l[c * 256 + k] = f2bf(v - bf2f(h));
    } else if (k < 128) {                        // Wmu|Wsig -> [256 cols][128 k]
        int c2 = c - 128;
        float v = (c2 < 128) ? Wmu[k * 128 + c2] : Wsig[k * 128 + (c2 - 128)];
        unsigned short h = f2bf(v);
        Wmsh[c2 * 128 + k] = h;
        Wmsl[c2 * 128 + k] = f2bf(v - bf2f(h));
    }
}

// ---------------- GEMM1: t0_bf16 = x @ W0 (2-term W comp, A=W, LDS flush) -------------
// 256 thr = 4 waves x 32 nodes. W ct-chunks (16 cols x 256k x hi/lo = 16KB) dbuf'd;
// t0 accumulated into 32KB LDS out-buffer, flushed contiguously to t0base/t0stride.

__launch_bounds__(256, 2)
__global__ void gemm1_mfma(const float* __restrict__ x,
                           const unsigned short* __restrict__ Wh,
                           const unsigned short* __restrict__ Wl,
                           char* __restrict__ t0base, int t0stride) {
    __shared__ __align__(16) char L[65536];      // [0,32K): W dbuf; [32K,64K): t0 out
    const int tid = threadIdx.x;
    const int wave = tid >> 6, lane = tid & 63;
    const int lrow = lane & 15, q4 = lane >> 4;
    const int swz = (lrow & 7) << 4;
    const int n0 = blockIdx.x * 128;

    // B operand: wave's 32 x-rows packed to bf16 regs (read once, K=256)
    bf16x8 b[2][8];
    #pragma unroll
    for (int g = 0; g < 2; g++) {
        int node = n0 + wave * 32 + g * 16 + lrow;
        int nc = node > N_NODES - 1 ? N_NODES - 1 : node;
        const float* xp = x + (size_t)nc * 256 + q4 * 8;
        #pragma unroll
        for (int ks = 0; ks < 8; ks++) {
            float4 p0 = *(const float4*)(xp + ks * 32);
            float4 p1 = *(const float4*)(xp + ks * 32 + 4);
            b[g][ks] = packhi(p0, p1);
        }
    }

    // staging map: 1024x16B units; u = tid + 256j; hl=u>>9, col=(u>>5)&15, k8=(u&31)*8
    int sgo[4], slo[4];
    #pragma unroll
    for (int j = 0; j < 4; j++) {
        int u = tid + 256 * j;
        int col = (u >> 5) & 15, k8 = (u & 31) * 8;
        sgo[j] = col * 256 + k8;
        slo[j] = (j >= 2 ? 8192 : 0) + ((col * 512 + k8 * 2) ^ ((col & 7) << 4));
    }

    {   // stage ct 0
        int4 sw[4];
        #pragma unroll
        for (int j = 0; j < 4; j++)
            sw[j] = *(const int4*)((j >= 2 ? Wl : Wh) + sgo[j]);
        #pragma unroll
        for (int j = 0; j < 4; j++)
            *(int4*)(L + slo[j]) = sw[j];
    }
    __syncthreads();

    #pragma unroll
    for (int ct = 0; ct < 8; ct++) {
        int4 sw[4];
        if (ct < 7) {
            #pragma unroll
            for (int j = 0; j < 4; j++)
                sw[j] = *(const int4*)((j >= 2 ? Wl : Wh) + (ct + 1) * 16 * 256 + sgo[j]);
        }
        const char* bufp = L + (ct & 1) * 16384;
        f32x4 acc[2] = {};
        #pragma unroll
        for (int hl = 0; hl < 2; hl++) {
            bf16x8 w[8];
            #pragma unroll
            for (int ks = 0; ks < 8; ks++)
                w[ks] = *(const bf16x8*)(bufp + hl * 8192 +
                        ((lrow * 512 + ks * 64 + q4 * 16) ^ swz));
            #pragma unroll
            for (int g = 0; g < 2; g++)
                #pragma unroll
                for (int ks = 0; ks < 8; ks++)
                    acc[g] = MFMA16(w[ks], b[g][ks], acc[g]);
        }
        // acc -> t0 out-buffer (bf16, swizzled)
        #pragma unroll
        for (int g = 0; g < 2; g++) {
            int node_l = wave * 32 + g * 16 + lrow;
            int a = (node_l * 256 + ct * 32 + q4 * 8) ^ ((node_l & 7) << 4);
            ushort4 p = make_ushort4(f2bf(acc[g][0]), f2bf(acc[g][1]),
                                     f2bf(acc[g][2]), f2bf(acc[g][3]));
            *(ushort4*)(L + 32768 + a) = p;
        }
        if (ct < 7) {
            #pragma unroll
            for (int j = 0; j < 4; j++)
                *(int4*)(L + (((ct + 1) & 1) * 16384) + slo[j]) = sw[j];
            __syncthreads();
        }
    }
    __syncthreads();
    // flush t0: 32KB contiguous per block
    #pragma unroll
    for (int it = 0; it < 8; it++) {
        int linear = it * 4096 + tid * 16;
        int node_l = linear >> 8, off = linear & 255;
        int4 v = *(const int4*)(L + 32768 + (linear ^ ((node_l & 7) << 4)));
        int node = n0 + node_l;
        if (node < N_NODES)
            *(int4*)(t0base + (size_t)node * t0stride + off) = v;
    }
}

// ---------------- aggregation: scalarized edge processing (stride-parameterized) -------

template <int EPI>
__launch_bounds__(256)
__global__ void agg_bf16(const char* __restrict__ srcBase, char* __restrict__ dstBase,
                         int stride,
                         const int* __restrict__ offs, const int* __restrict__ cnt,
                         const int* __restrict__ sortedRow, const float* __restrict__ dinv,
                         const float* __restrict__ bias) {
    const int n = blockIdx.x * 4 + (threadIdx.x >> 6);
    const int lane = threadIdx.x & 63;
    const int laneB = lane * 4;
    const float dn = dinv[n];
    unsigned int u = *(const unsigned int*)(srcBase + (size_t)n * stride + laneB);
    const float ws = dn * dn;
    float acc0 = ws * bf_lo(u);
    float acc1 = ws * bf_hi(u);
    const int start = __builtin_amdgcn_readfirstlane(offs[n]);
    const int num   = __builtin_amdgcn_readfirstlane(cnt[n]);

    int i = 0;
    for (; i + 8 <= num; i += 8) {
        int myr = sortedRow[start + i + (lane & 7)];
        int rs[8];
        #pragma unroll
        for (int j = 0; j < 8; j++) rs[j] = __builtin_amdgcn_readlane(myr, j);
        unsigned int ue[8];
        #pragma unroll
        for (int j = 0; j < 8; j++) {
            const char* p = srcBase + (size_t)rs[j] * stride;   // SGPR base
            ue[j] = *(const unsigned int*)(p + laneB);
        }
        float w[8];
        #pragma unroll
        for (int j = 0; j < 8; j++) w[j] = dn * dinv[rs[j]];
        #pragma unroll
        for (int j = 0; j < 8; j++) {
            acc0 = fmaf(w[j], bf_lo(ue[j]), acc0);
            acc1 = fmaf(w[j], bf_hi(ue[j]), acc1);
        }
    }
    for (; i < num; i++) {
        int rsv = __builtin_amdgcn_readfirstlane(sortedRow[start + i]);
        const char* p = srcBase + (size_t)rsv * stride;
        unsigned int ue = *(const unsigned int*)(p + laneB);
        float w = dn * dinv[rsv];
        acc0 = fmaf(w, bf_lo(ue), acc0);
        acc1 = fmaf(w, bf_hi(ue), acc1);
    }

    if (EPI) {
        acc0 = fmaxf(acc0 + bias[2 * lane], 0.f);
        acc1 = fmaxf(acc1 + bias[2 * lane + 1], 0.f);
    }
    unsigned int o = (unsigned int)f2bf(acc0) | ((unsigned int)f2bf(acc1) << 16);
    *(unsigned int*)(dstBase + (size_t)n * stride + laneB) = o;
}

// ---------------- GEMM2: [mu|sigma] = t2 @ [Wmu|Wsig] (2-term, nt stores) --------------
// 256 thr = 4 waves x 32 nodes. 16 ct chunks (16 cols x 128k x hi/lo = 8KB) dbuf'd
// (LDS 16KB -> high occupancy). t2 reads in prologue (legacy in-place safe: each block
// reads/writes only its own node rows). mu/sigma via nontemporal dwordx4 stores.

__launch_bounds__(256, 4)
__global__ void gemm2_mfma(const unsigned short* __restrict__ Wh,
                           const unsigned short* __restrict__ Wl,
                           const float* __restrict__ bmu, const float* __restrict__ bsig,
                           const char* __restrict__ t2base, int t2stride,
                           char* __restrict__ outc) {
    __shared__ __align__(16) char L[16384];
    const int tid = threadIdx.x;
    const int wave = tid >> 6, lane = tid & 63;
    const int lrow = lane & 15, q4 = lane >> 4;
    const int swz = (lrow & 7) << 4;
    const int n0 = blockIdx.x * 128;

    bf16x8 b[2][4];
    int nodes[2];
    #pragma unroll
    for (int g = 0; g < 2; g++) {
        int node = n0 + wave * 32 + g * 16 + lrow;
        nodes[g] = node;
        int nc = node > N_NODES - 1 ? N_NODES - 1 : node;
        const char* ap = t2base + (size_t)nc * t2stride + q4 * 16;
        #pragma unroll
        for (int ki = 0; ki < 4; ki++)
            b[g][ki] = *(const bf16x8*)(ap + ki * 64);
    }

    const int colS = tid >> 4, k8S = (tid & 15) * 8;
    const int sgo = colS * 128 + k8S;
    const int sloc = (colS * 256 + k8S * 2) ^ ((colS & 7) << 4);

    {   // stage ct 0
        int4 h = *(const int4*)(Wh + sgo);
        int4 l = *(const int4*)(Wl + sgo);
        *(int4*)(L + sloc) = h;
        *(int4*)(L + 4096 + sloc) = l;
    }
    __syncthreads();

    #pragma unroll
    for (int ct = 0; ct < 16; ct++) {
        int4 swh, swl;
        if (ct < 15) {
            swh = *(const int4*)(Wh + (ct + 1) * 2048 + sgo);
            swl = *(const int4*)(Wl + (ct + 1) * 2048 + sgo);
        }
        const char* bufp = L + (ct & 1) * 8192;
        f32x4 acc[2] = {};
        #pragma unroll
        for (int hl = 0; hl < 2; hl++) {
            bf16x8 w[4];
            #pragma unroll
            for (int ki = 0; ki < 4; ki++)
                w[ki] = *(const bf16x8*)(bufp + hl * 4096 +
                        ((lrow * 256 + ki * 64 + q4 * 16) ^ swz));
            #pragma unroll
            for (int g = 0; g < 2; g++)
                #pragma unroll
                for (int ki = 0; ki < 4; ki++)
                    acc[g] = MFMA16(w[ki], b[g][ki], acc[g]);
        }
        const int f0 = (ct & 7) * 16 + q4 * 4;
        if (ct < 8) {                            // mu cols
            float4 bv = *(const float4*)(bmu + f0);
            #pragma unroll
            for (int g = 0; g < 2; g++)
                if (nodes[g] < N_NODES) {
                    f32x4 o = {acc[g][0] + bv.x, acc[g][1] + bv.y,
                               acc[g][2] + bv.z, acc[g][3] + bv.w};
                    ntstore4(outc + (size_t)nodes[g] * ROWB + f0 * 4, o);
                }
        } else {                                 // sigma cols (softplus)
            float4 bv = *(const float4*)(bsig + f0);
            #pragma unroll
            for (int g = 0; g < 2; g++)
                if (nodes[g] < N_NODES) {
                    f32x4 o;
                    #pragma unroll
                    for (int q = 0; q < 4; q++) {
                        float xv = acc[g][q] + ((const float*)&bv)[q];
                        o[q] = fmaxf(xv, 0.f) + log1pf(expf(-fabsf(xv))) + 1e-7f;
                    }
                    ntstore4(outc + HALFB + (size_t)nodes[g] * ROWB + f0 * 4, o);
                }
        }
        if (ct < 15) {
            char* nb = L + ((ct + 1) & 1) * 8192;
            *(int4*)(nb + sloc) = swh;
            *(int4*)(nb + 4096 + sloc) = swl;
            __syncthreads();
        }
    }
}

// ---------------- launch ----------------

extern "C" void kernel_launch(void* const* d_in, const int* in_sizes, int n_in,
                              void* d_out, int out_size, void* d_ws, size_t ws_size,
                              hipStream_t stream) {
    const float* x    = (const float*)d_in[0];
    const int*   ei   = (const int*)d_in[1];
    const int*   row  = ei;
    const int*   col  = ei + N_EDGES;
    const float* W0   = (const float*)d_in[2];
    const float* b0   = (const float*)d_in[3];
    const float* Wmu  = (const float*)d_in[4];
    const float* bmu  = (const float*)d_in[5];
    const float* Wsig = (const float*)d_in[6];
    const float* bsig = (const float*)d_in[7];
    char* outc = (char*)d_out;
    char* wsb  = (char*)d_ws;

    // linear ws layout (256B-aligned fields)
    size_t o = 0;
    auto take = [&](size_t nbytes) {
        size_t r = o; o += (nbytes + 255) & ~(size_t)255; return r;
    };
    size_t oW0h = take(65536), oW0l = take(65536);
    size_t oWmsh = take(65536), oWmsl = take(65536);
    size_t oGcur = take(NBKT * 4), oBkt = take(NBKT * 4);
    size_t oCnt = take(N_NODES * 4), oOffs = take(N_NODES * 4), oDinv = take(N_NODES * 4);
    size_t oSort = take(N_EDGES * 4);
    size_t oEnt = take((size_t)NBKT * BCAP * 8);
    size_t oT0 = take((size_t)N_NODES * 256);
    size_t oH  = take((size_t)N_NODES * 256);
    const bool dense = (ws_size >= o);

    unsigned short* W0h  = (unsigned short*)(wsb + oW0h);
    unsigned short* W0l  = (unsigned short*)(wsb + oW0l);
    unsigned short* Wmsh = (unsigned short*)(wsb + oWmsh);
    unsigned short* Wmsl = (unsigned short*)(wsb + oWmsl);
    int*   gcur      = (int*)(wsb + oGcur);
    int*   bktBase   = (int*)(wsb + oBkt);
    int*   cnt       = (int*)(wsb + oCnt);
    int*   offs      = (int*)(wsb + oOffs);
    float* dinvp     = (float*)(wsb + oDinv);
    int*   sortedRow = (int*)(wsb + oSort);

    u64* entries; char *t0b, *hb, *t2b; int stride;
    if (dense) {
        entries = (u64*)(wsb + oEnt);
        t0b = wsb + oT0;  hb = wsb + oH;  t2b = wsb + oT0;   // t2 reuses t0 space
        stride = 256;
    } else {
        entries = (u64*)(outc + HALFB);
        t0b = outc + 256; hb = outc + HALFB; t2b = outc;
        stride = ROWB;
    }

    hipMemsetAsync(gcur, 0, NBKT * sizeof(int), stream);
    prep_w<<<384, 256, 0, stream>>>(W0, Wmu, Wsig, W0h, W0l, Wmsh, Wmsl);
    bin_kernel<<<(N_EDGES + EPB - 1) / EPB, 256, 0, stream>>>(row, col, gcur, entries);
    bktscan_kernel<<<1, 256, 0, stream>>>(gcur, bktBase);
    csr_kernel<<<NBKT, 256, 0, stream>>>(entries, gcur, bktBase, cnt, offs, dinvp, sortedRow);

    gemm1_mfma<<<(N_NODES + 127) / 128, 256, 0, stream>>>(x, W0h, W0l, t0b, stride);
    agg_bf16<1><<<N_NODES / 4, 256, 0, stream>>>(t0b, hb, stride,
                                                 offs, cnt, sortedRow, dinvp, b0);
    agg_bf16<0><<<N_NODES / 4, 256, 0, stream>>>(hb, t2b, stride,
                                                 offs, cnt, sortedRow, dinvp, nullptr);
    gemm2_mfma<<<(N_NODES + 127) / 128, 256, 0, stream>>>(Wmsh, Wmsl, bmu, bsig,
                                                          t2b, stride, outc);
}

// Round 13
// 279.872 us; speedup vs baseline: 1.3366x; 1.1114x over previous
//
#include <hip/hip_runtime.h>
#include <math.h>

#define N_NODES 100000
#define N_EDGES 1600000
#define ROWB    512                 // bytes per row slot in d_out (legacy layout)
#define HALFB   51200000ull         // byte offset of second output (sigma half)
#define NBKT    196                 // sort buckets (512 dst nodes each)
#define BSH     9
#define BCAP    10240               // entries per bucket (mean 8192, >20 sigma margin)
#define EPB     1024                // edges per bin block

typedef float  f32x4  __attribute__((ext_vector_type(4)));
typedef __bf16 bf16x8 __attribute__((ext_vector_type(8)));
typedef short  s16x8  __attribute__((ext_vector_type(8)));
typedef unsigned long long u64;

__device__ __forceinline__ unsigned short f2bf(float f) {
    unsigned int u = __builtin_bit_cast(unsigned int, f);
    u += 0x7FFFu + ((u >> 16) & 1u);          // RNE
    return (unsigned short)(u >> 16);
}
__device__ __forceinline__ float bf2f(unsigned short h) {
    unsigned int u = ((unsigned int)h) << 16;
    return __builtin_bit_cast(float, u);
}
__device__ __forceinline__ float bf_lo(unsigned int u) {
    return __builtin_bit_cast(float, u << 16);
}
__device__ __forceinline__ float bf_hi(unsigned int u) {
    return __builtin_bit_cast(float, u & 0xFFFF0000u);
}
__device__ __forceinline__ bf16x8 packhi(const float4& a, const float4& b) {
    float v[8] = {a.x, a.y, a.z, a.w, b.x, b.y, b.z, b.w};
    s16x8 hh;
    #pragma unroll
    for (int j = 0; j < 8; j++) hh[j] = (short)f2bf(v[j]);
    return __builtin_bit_cast(bf16x8, hh);
}
__device__ __forceinline__ void ntstore4(void* p, f32x4 v) {
    __builtin_nontemporal_store(v, (f32x4*)p);
}
// fast softplus: max(x,0) + ln(1 + e^-|x|) + 1e-7, via v_exp/v_log fast intrinsics
__device__ __forceinline__ float fast_sp(float x) {
    return fmaxf(x, 0.f) + __logf(1.f + __expf(-fabsf(x))) + 1e-7f;
}

#define MFMA16(a, b, c) __builtin_amdgcn_mfma_f32_16x16x32_bf16((a), (b), (c), 0, 0, 0)

// ---------------- sort pass B: bucket-binning ----------------

__launch_bounds__(256)
__global__ void bin_kernel(const int* __restrict__ row, const int* __restrict__ col,
                           int* __restrict__ gcur, u64* __restrict__ entries) {
    __shared__ int hist[NBKT], base[NBKT], cur[NBKT];
    const int tid = threadIdx.x;
    for (int i = tid; i < NBKT; i += 256) { hist[i] = 0; cur[i] = 0; }
    __syncthreads();
    const int e0 = blockIdx.x * EPB;
    int cols[4];
    #pragma unroll
    for (int it = 0; it < 4; it++) {
        int e = e0 + it * 256 + tid;
        int c = (e < N_EDGES) ? col[e] : -1;
        cols[it] = c;
        if (c >= 0) atomicAdd(&hist[c >> BSH], 1);
    }
    __syncthreads();
    for (int i = tid; i < NBKT; i += 256)
        base[i] = atomicAdd(&gcur[i], hist[i]);
    __syncthreads();
    #pragma unroll
    for (int it = 0; it < 4; it++) {
        int e = e0 + it * 256 + tid;
        int c = cols[it];
        if (c >= 0) {
            int b = c >> BSH;
            int r = atomicAdd(&cur[b], 1);
            entries[(size_t)b * BCAP + base[b] + r] =
                ((u64)(unsigned)c << 32) | (unsigned)row[e];
        }
    }
}

// ---------------- bucket-base scan (196 values, 1 block) ----------------

__global__ void bktscan_kernel(const int* __restrict__ gcur, int* __restrict__ bktBase) {
    __shared__ int s[256];
    const int tid = threadIdx.x;
    int v = (tid < NBKT) ? gcur[tid] : 0;
    s[tid] = v;
    __syncthreads();
    for (int d = 1; d < 256; d <<= 1) {
        int t = (tid >= d) ? s[tid - d] : 0;
        __syncthreads();
        s[tid] += t;
        __syncthreads();
    }
    if (tid < NBKT) bktBase[tid] = s[tid] - v;
}

// ---------------- sort pass C: per-bucket histogram + scan + scatter ----------------

__launch_bounds__(256)
__global__ void csr_kernel(const u64* __restrict__ entries, const int* __restrict__ gcur,
                           const int* __restrict__ bktBase,
                           int* __restrict__ cnt, int* __restrict__ offs,
                           float* __restrict__ dinv, int* __restrict__ sortedRow) {
    __shared__ int lcnt[512], sA[512], sB[512], lcur[512];
    const int b = blockIdx.x, tid = threadIdx.x;
    const int n0 = b << BSH;
    lcnt[tid] = 0; lcnt[tid + 256] = 0;
    __syncthreads();
    const int nb = gcur[b], base = bktBase[b];
    const u64* ep = entries + (size_t)b * BCAP;
    for (int i = tid; i < nb; i += 256)
        atomicAdd(&lcnt[(int)(ep[i] >> 32) - n0], 1);
    __syncthreads();
    sA[tid] = lcnt[tid]; sA[tid + 256] = lcnt[tid + 256];
    __syncthreads();
    int* src = sA; int* dst = sB;
    for (int d = 1; d < 512; d <<= 1) {
        #pragma unroll
        for (int k = tid; k < 512; k += 256)
            dst[k] = src[k] + ((k >= d) ? src[k - d] : 0);
        __syncthreads();
        int* t = src; src = dst; dst = t;
    }
    #pragma unroll
    for (int k = tid; k < 512; k += 256) {
        int excl = src[k] - lcnt[k];
        lcur[k] = excl;
        int node = n0 + k;
        if (node < N_NODES) {
            offs[node] = base + excl;
            cnt[node]  = lcnt[k];
            dinv[node] = rsqrtf((float)(lcnt[k] + 1));   // +1 self loop
        }
    }
    __syncthreads();
    for (int i = tid; i < nb; i += 256) {
        u64 pk = ep[i];
        int local = (int)(pk >> 32) - n0;
        int p = base + atomicAdd(&lcur[local], 1);
        sortedRow[p] = (int)(pk & 0xFFFFFFFFu);
    }
}

// ---------------- weight pre-transpose ----------------

__global__ void prep_w(const float* __restrict__ W0, const float* __restrict__ Wmu,
                       const float* __restrict__ Wsig,
                       unsigned short* __restrict__ W0h, unsigned short* __restrict__ W0l,
                       unsigned short* __restrict__ Wmsh, unsigned short* __restrict__ Wmsl) {
    int c = blockIdx.x;
    int k = threadIdx.x;
    if (c < 128) {                               // W0 [256][128] -> [128 cols][256 k]
        float v = W0[k * 128 + c];
        unsigned short h = f2bf(v);
        W0h[c * 256 + k] = h;
        W0l[c * 256 + k] = f2bf(v - bf2f(h));
    } else if (k < 128) {                        // Wmu|Wsig -> [256 cols][128 k]
        int c2 = c - 128;
        float v = (c2 < 128) ? Wmu[k * 128 + c2] : Wsig[k * 128 + (c2 - 128)];
        unsigned short h = f2bf(v);
        Wmsh[c2 * 128 + k] = h;
        Wmsl[c2 * 128 + k] = f2bf(v - bf2f(h));
    }
}

// ---------------- GEMM1: t0_bf16 = x @ W0 (2-term W comp, A=W, LDS flush) -------------
// 256 thr = 4 waves x 16 nodes (64 nodes/block, grid 1563). W ct-chunks (16 cols x
// 256k x hi/lo = 16KB) dbuf'd; t0 into 16KB LDS out-buffer, flushed contiguously.

__launch_bounds__(256, 3)
__global__ void gemm1_mfma(const float* __restrict__ x,
                           const unsigned short* __restrict__ Wh,
                           const unsigned short* __restrict__ Wl,
                           char* __restrict__ t0base, int t0stride) {
    __shared__ __align__(16) char L[49152];      // [0,32K): W dbuf; [32K,48K): t0 out
    const int tid = threadIdx.x;
    const int wave = tid >> 6, lane = tid & 63;
    const int lrow = lane & 15, q4 = lane >> 4;
    const int swz = (lrow & 7) << 4;
    const int n0 = blockIdx.x * 64;

    // B operand: wave's 16 x-rows packed to bf16 regs (read once, K=256)
    bf16x8 b[8];
    {
        int node = n0 + wave * 16 + lrow;
        int nc = node > N_NODES - 1 ? N_NODES - 1 : node;
        const float* xp = x + (size_t)nc * 256 + q4 * 8;
        #pragma unroll
        for (int ks = 0; ks < 8; ks++) {
            float4 p0 = *(const float4*)(xp + ks * 32);
            float4 p1 = *(const float4*)(xp + ks * 32 + 4);
            b[ks] = packhi(p0, p1);
        }
    }

    // staging map: 1024x16B units; u = tid + 256j; hl=u>>9, col=(u>>5)&15, k8=(u&31)*8
    int sgo[4], slo[4];
    #pragma unroll
    for (int j = 0; j < 4; j++) {
        int u = tid + 256 * j;
        int col = (u >> 5) & 15, k8 = (u & 31) * 8;
        sgo[j] = col * 256 + k8;
        slo[j] = (j >= 2 ? 8192 : 0) + ((col * 512 + k8 * 2) ^ ((col & 7) << 4));
    }

    {   // stage ct 0
        int4 sw[4];
        #pragma unroll
        for (int j = 0; j < 4; j++)
            sw[j] = *(const int4*)((j >= 2 ? Wl : Wh) + sgo[j]);
        #pragma unroll
        for (int j = 0; j < 4; j++)
            *(int4*)(L + slo[j]) = sw[j];
    }
    __syncthreads();

    #pragma unroll
    for (int ct = 0; ct < 8; ct++) {
        int4 sw[4];
        if (ct < 7) {
            #pragma unroll
            for (int j = 0; j < 4; j++)
                sw[j] = *(const int4*)((j >= 2 ? Wl : Wh) + (ct + 1) * 16 * 256 + sgo[j]);
        }
        const char* bufp = L + (ct & 1) * 16384;
        f32x4 acc = {};
        #pragma unroll
        for (int hl = 0; hl < 2; hl++) {
            bf16x8 w[8];
            #pragma unroll
            for (int ks = 0; ks < 8; ks++)
                w[ks] = *(const bf16x8*)(bufp + hl * 8192 +
                        ((lrow * 512 + ks * 64 + q4 * 16) ^ swz));
            #pragma unroll
            for (int ks = 0; ks < 8; ks++)
                acc = MFMA16(w[ks], b[ks], acc);
        }
        // acc -> t0 out-buffer (bf16, swizzled)
        {
            int node_l = wave * 16 + lrow;
            int a = (node_l * 256 + ct * 32 + q4 * 8) ^ ((node_l & 7) << 4);
            ushort4 p = make_ushort4(f2bf(acc[0]), f2bf(acc[1]),
                                     f2bf(acc[2]), f2bf(acc[3]));
            *(ushort4*)(L + 32768 + a) = p;
        }
        if (ct < 7) {
            #pragma unroll
            for (int j = 0; j < 4; j++)
                *(int4*)(L + (((ct + 1) & 1) * 16384) + slo[j]) = sw[j];
            __syncthreads();
        }
    }
    __syncthreads();
    // flush t0: 16KB contiguous per block
    #pragma unroll
    for (int it = 0; it < 4; it++) {
        int linear = it * 4096 + tid * 16;
        int node_l = linear >> 8, off = linear & 255;
        int4 v = *(const int4*)(L + 32768 + (linear ^ ((node_l & 7) << 4)));
        int node = n0 + node_l;
        if (node < N_NODES)
            *(int4*)(t0base + (size_t)node * t0stride + off) = v;
    }
}

// ---------------- aggregation: scalarized edge processing (stride-parameterized) -------

template <int EPI>
__launch_bounds__(256)
__global__ void agg_bf16(const char* __restrict__ srcBase, char* __restrict__ dstBase,
                         int stride,
                         const int* __restrict__ offs, const int* __restrict__ cnt,
                         const int* __restrict__ sortedRow, const float* __restrict__ dinv,
                         const float* __restrict__ bias) {
    const int n = blockIdx.x * 4 + (threadIdx.x >> 6);
    const int lane = threadIdx.x & 63;
    const int laneB = lane * 4;
    const float dn = dinv[n];
    unsigned int u = *(const unsigned int*)(srcBase + (size_t)n * stride + laneB);
    const float ws = dn * dn;
    float acc0 = ws * bf_lo(u);
    float acc1 = ws * bf_hi(u);
    const int start = __builtin_amdgcn_readfirstlane(offs[n]);
    const int num   = __builtin_amdgcn_readfirstlane(cnt[n]);

    int i = 0;
    for (; i + 8 <= num; i += 8) {
        int myr = sortedRow[start + i + (lane & 7)];
        int rs[8];
        #pragma unroll
        for (int j = 0; j < 8; j++) rs[j] = __builtin_amdgcn_readlane(myr, j);
        unsigned int ue[8];
        #pragma unroll
        for (int j = 0; j < 8; j++) {
            const char* p = srcBase + (size_t)rs[j] * stride;   // SGPR base
            ue[j] = *(const unsigned int*)(p + laneB);
        }
        float w[8];
        #pragma unroll
        for (int j = 0; j < 8; j++) w[j] = dn * dinv[rs[j]];
        #pragma unroll
        for (int j = 0; j < 8; j++) {
            acc0 = fmaf(w[j], bf_lo(ue[j]), acc0);
            acc1 = fmaf(w[j], bf_hi(ue[j]), acc1);
        }
    }
    for (; i < num; i++) {
        int rsv = __builtin_amdgcn_readfirstlane(sortedRow[start + i]);
        const char* p = srcBase + (size_t)rsv * stride;
        unsigned int ue = *(const unsigned int*)(p + laneB);
        float w = dn * dinv[rsv];
        acc0 = fmaf(w, bf_lo(ue), acc0);
        acc1 = fmaf(w, bf_hi(ue), acc1);
    }

    if (EPI) {
        acc0 = fmaxf(acc0 + bias[2 * lane], 0.f);
        acc1 = fmaxf(acc1 + bias[2 * lane + 1], 0.f);
    }
    unsigned int o = (unsigned int)f2bf(acc0) | ((unsigned int)f2bf(acc1) << 16);
    *(unsigned int*)(dstBase + (size_t)n * stride + laneB) = o;
}

// ---------------- GEMM2: [mu|sigma] = t2 @ [Wmu|Wsig] (2-term, nt stores) --------------
// 256 thr = 4 waves x 16 nodes (64 nodes/block, grid 1563). 16 ct chunks (16 cols x
// 128k x hi/lo = 8KB) dbuf'd; fast softplus; nontemporal output stores.

__launch_bounds__(256, 4)
__global__ void gemm2_mfma(const unsigned short* __restrict__ Wh,
                           const unsigned short* __restrict__ Wl,
                           const float* __restrict__ bmu, const float* __restrict__ bsig,
                           const char* __restrict__ t2base, int t2stride,
                           char* __restrict__ outc) {
    __shared__ __align__(16) char L[16384];
    const int tid = threadIdx.x;
    const int wave = tid >> 6, lane = tid & 63;
    const int lrow = lane & 15, q4 = lane >> 4;
    const int swz = (lrow & 7) << 4;
    const int n0 = blockIdx.x * 64;

    const int node = n0 + wave * 16 + lrow;
    const bool ok = node < N_NODES;
    bf16x8 b[4];
    {
        int nc = node > N_NODES - 1 ? N_NODES - 1 : node;
        const char* ap = t2base + (size_t)nc * t2stride + q4 * 16;
        #pragma unroll
        for (int ki = 0; ki < 4; ki++)
            b[ki] = *(const bf16x8*)(ap + ki * 64);
    }

    const int colS = tid >> 4, k8S = (tid & 15) * 8;
    const int sgo = colS * 128 + k8S;
    const int sloc = (colS * 256 + k8S * 2) ^ ((colS & 7) << 4);

    {   // stage ct 0
        int4 h = *(const int4*)(Wh + sgo);
        int4 l = *(const int4*)(Wl + sgo);
        *(int4*)(L + sloc) = h;
        *(int4*)(L + 4096 + sloc) = l;
    }
    __syncthreads();

    #pragma unroll
    for (int ct = 0; ct < 16; ct++) {
        int4 swh, swl;
        if (ct < 15) {
            swh = *(const int4*)(Wh + (ct + 1) * 2048 + sgo);
            swl = *(const int4*)(Wl + (ct + 1) * 2048 + sgo);
        }
        const char* bufp = L + (ct & 1) * 8192;
        f32x4 acc = {};
        #pragma unroll
        for (int hl = 0; hl < 2; hl++) {
            bf16x8 w[4];
            #pragma unroll
            for (int ki = 0; ki < 4; ki++)
                w[ki] = *(const bf16x8*)(bufp + hl * 4096 +
                        ((lrow * 256 + ki * 64 + q4 * 16) ^ swz));
            #pragma unroll
            for (int ki = 0; ki < 4; ki++)
                acc = MFMA16(w[ki], b[ki], acc);
        }
        const int f0 = (ct & 7) * 16 + q4 * 4;
        if (ct < 8) {                            // mu cols
            if (ok) {
                float4 bv = *(const float4*)(bmu + f0);
                f32x4 o = {acc[0] + bv.x, acc[1] + bv.y, acc[2] + bv.z, acc[3] + bv.w};
                ntstore4(outc + (size_t)node * ROWB + f0 * 4, o);
            }
        } else {                                 // sigma cols (fast softplus)
            if (ok) {
                float4 bv = *(const float4*)(bsig + f0);
                f32x4 o;
                #pragma unroll
                for (int q = 0; q < 4; q++)
                    o[q] = fast_sp(acc[q] + ((const float*)&bv)[q]);
                ntstore4(outc + HALFB + (size_t)node * ROWB + f0 * 4, o);
            }
        }
        if (ct < 15) {
            char* nb = L + ((ct + 1) & 1) * 8192;
            *(int4*)(nb + sloc) = swh;
            *(int4*)(nb + 4096 + sloc) = swl;
            __syncthreads();
        }
    }
}

// ---------------- launch ----------------

extern "C" void kernel_launch(void* const* d_in, const int* in_sizes, int n_in,
                              void* d_out, int out_size, void* d_ws, size_t ws_size,
                              hipStream_t stream) {
    const float* x    = (const float*)d_in[0];
    const int*   ei   = (const int*)d_in[1];
    const int*   row  = ei;
    const int*   col  = ei + N_EDGES;
    const float* W0   = (const float*)d_in[2];
    const float* b0   = (const float*)d_in[3];
    const float* Wmu  = (const float*)d_in[4];
    const float* bmu  = (const float*)d_in[5];
    const float* Wsig = (const float*)d_in[6];
    const float* bsig = (const float*)d_in[7];
    char* outc = (char*)d_out;
    char* wsb  = (char*)d_ws;

    // linear ws layout (256B-aligned fields)
    size_t o = 0;
    auto take = [&](size_t nbytes) {
        size_t r = o; o += (nbytes + 255) & ~(size_t)255; return r;
    };
    size_t oW0h = take(65536), oW0l = take(65536);
    size_t oWmsh = take(65536), oWmsl = take(65536);
    size_t oGcur = take(NBKT * 4), oBkt = take(NBKT * 4);
    size_t oCnt = take(N_NODES * 4), oOffs = take(N_NODES * 4), oDinv = take(N_NODES * 4);
    size_t oSort = take(N_EDGES * 4);
    size_t oEnt = take((size_t)NBKT * BCAP * 8);
    size_t oT0 = take((size_t)N_NODES * 256);
    size_t oH  = take((size_t)N_NODES * 256);
    const bool dense = (ws_size >= o);

    unsigned short* W0h  = (unsigned short*)(wsb + oW0h);
    unsigned short* W0l  = (unsigned short*)(wsb + oW0l);
    unsigned short* Wmsh = (unsigned short*)(wsb + oWmsh);
    unsigned short* Wmsl = (unsigned short*)(wsb + oWmsl);
    int*   gcur      = (int*)(wsb + oGcur);
    int*   bktBase   = (int*)(wsb + oBkt);
    int*   cnt       = (int*)(wsb + oCnt);
    int*   offs      = (int*)(wsb + oOffs);
    float* dinvp     = (float*)(wsb + oDinv);
    int*   sortedRow = (int*)(wsb + oSort);

    u64* entries; char *t0b, *hb, *t2b; int stride;
    if (dense) {
        entries = (u64*)(wsb + oEnt);
        t0b = wsb + oT0;  hb = wsb + oH;  t2b = wsb + oT0;   // t2 reuses t0 space
        stride = 256;
    } else {
        entries = (u64*)(outc + HALFB);
        t0b = outc + 256; hb = outc + HALFB; t2b = outc;
        stride = ROWB;
    }

    hipMemsetAsync(gcur, 0, NBKT * sizeof(int), stream);
    prep_w<<<384, 256, 0, stream>>>(W0, Wmu, Wsig, W0h, W0l, Wmsh, Wmsl);
    bin_kernel<<<(N_EDGES + EPB - 1) / EPB, 256, 0, stream>>>(row, col, gcur, entries);
    bktscan_kernel<<<1, 256, 0, stream>>>(gcur, bktBase);
    csr_kernel<<<NBKT, 256, 0, stream>>>(entries, gcur, bktBase, cnt, offs, dinvp, sortedRow);

    gemm1_mfma<<<(N_NODES + 63) / 64, 256, 0, stream>>>(x, W0h, W0l, t0b, stride);
    agg_bf16<1><<<N_NODES / 4, 256, 0, stream>>>(t0b, hb, stride,
                                                 offs, cnt, sortedRow, dinvp, b0);
    agg_bf16<0><<<N_NODES / 4, 256, 0, stream>>>(hb, t2b, stride,
                                                 offs, cnt, sortedRow, dinvp, nullptr);
    gemm2_mfma<<<(N_NODES + 63) / 64, 256, 0, stream>>>(Wmsh, Wmsl, bmu, bsig,
                                                        t2b, stride, outc);
}

// Round 14
// 255.654 us; speedup vs baseline: 1.4632x; 1.0947x over previous
//
#include <hip/hip_runtime.h>
#include <math.h>

#define N_NODES 100000
#define N_EDGES 1600000
#define ROWB    512                 // bytes per row slot in d_out (legacy layout)
#define HALFB   51200000ull         // byte offset of second output (sigma half)
#define NBKT    196                 // sort buckets (512 dst nodes each)
#define BSH     9
#define BCAP    10240               // entries per bucket (mean 8192, >20 sigma margin)
#define EPB     1024                // edges per bin block
#define PREPB   384                 // prep_w blocks inside K1

typedef float  f32x4  __attribute__((ext_vector_type(4)));
typedef __bf16 bf16x8 __attribute__((ext_vector_type(8)));
typedef short  s16x8  __attribute__((ext_vector_type(8)));
typedef unsigned long long u64;

__device__ __forceinline__ unsigned short f2bf(float f) {
    unsigned int u = __builtin_bit_cast(unsigned int, f);
    u += 0x7FFFu + ((u >> 16) & 1u);          // RNE
    return (unsigned short)(u >> 16);
}
__device__ __forceinline__ float bf2f(unsigned short h) {
    unsigned int u = ((unsigned int)h) << 16;
    return __builtin_bit_cast(float, u);
}
__device__ __forceinline__ float bf_lo(unsigned int u) {
    return __builtin_bit_cast(float, u << 16);
}
__device__ __forceinline__ float bf_hi(unsigned int u) {
    return __builtin_bit_cast(float, u & 0xFFFF0000u);
}
__device__ __forceinline__ bf16x8 packhi(const float4& a, const float4& b) {
    float v[8] = {a.x, a.y, a.z, a.w, b.x, b.y, b.z, b.w};
    s16x8 hh;
    #pragma unroll
    for (int j = 0; j < 8; j++) hh[j] = (short)f2bf(v[j]);
    return __builtin_bit_cast(bf16x8, hh);
}
__device__ __forceinline__ void ntstore4(void* p, f32x4 v) {
    __builtin_nontemporal_store(v, (f32x4*)p);
}
__device__ __forceinline__ float fast_sp(float x) {
    return fmaxf(x, 0.f) + __logf(1.f + __expf(-fabsf(x))) + 1e-7f;
}

#define MFMA16(a, b, c) __builtin_amdgcn_mfma_f32_16x16x32_bf16((a), (b), (c), 0, 0, 0)

// ---------------- K1: prep_w (blocks 0..383) + bin (blocks 384..) -------------------

__launch_bounds__(256)
__global__ void k1_prep_bin(const float* __restrict__ W0, const float* __restrict__ Wmu,
                            const float* __restrict__ Wsig,
                            unsigned short* __restrict__ W0h, unsigned short* __restrict__ W0l,
                            unsigned short* __restrict__ Wmsh, unsigned short* __restrict__ Wmsl,
                            const int* __restrict__ row, const int* __restrict__ col,
                            int* __restrict__ gcur, u64* __restrict__ entries) {
    __shared__ int hist[NBKT], base[NBKT], cur[NBKT];
    const int tid = threadIdx.x;
    if (blockIdx.x < PREPB) {                    // ---- prep_w ----
        int c = blockIdx.x, k = tid;
        if (c < 128) {                           // W0 [256][128] -> [128 cols][256 k]
            float v = W0[k * 128 + c];
            unsigned short h = f2bf(v);
            W0h[c * 256 + k] = h;
            W0l[c * 256 + k] = f2bf(v - bf2f(h));
        } else if (k < 128) {                    // Wmu|Wsig -> [256 cols][128 k]
            int c2 = c - 128;
            float v = (c2 < 128) ? Wmu[k * 128 + c2] : Wsig[k * 128 + (c2 - 128)];
            unsigned short h = f2bf(v);
            Wmsh[c2 * 128 + k] = h;
            Wmsl[c2 * 128 + k] = f2bf(v - bf2f(h));
        }
        return;
    }
    // ---- bin ----
    const int bid = blockIdx.x - PREPB;
    for (int i = tid; i < NBKT; i += 256) { hist[i] = 0; cur[i] = 0; }
    __syncthreads();
    const int e0 = bid * EPB;
    int cols[4];
    #pragma unroll
    for (int it = 0; it < 4; it++) {
        int e = e0 + it * 256 + tid;
        int c = (e < N_EDGES) ? col[e] : -1;
        cols[it] = c;
        if (c >= 0) atomicAdd(&hist[c >> BSH], 1);
    }
    __syncthreads();
    for (int i = tid; i < NBKT; i += 256)
        base[i] = atomicAdd(&gcur[i], hist[i]);
    __syncthreads();
    #pragma unroll
    for (int it = 0; it < 4; it++) {
        int e = e0 + it * 256 + tid;
        int c = cols[it];
        if (c >= 0) {
            int b = c >> BSH;
            int r = atomicAdd(&cur[b], 1);
            entries[(size_t)b * BCAP + base[b] + r] =
                ((u64)(unsigned)c << 32) | (unsigned)row[e];
        }
    }
}

// ---------------- K2: csr (blocks 0..195, self-computed base) + gemm1 -----------------

__launch_bounds__(256, 3)
__global__ void k2_csr_gemm1(const u64* __restrict__ entries, const int* __restrict__ gcur,
                             int* __restrict__ cnt, int* __restrict__ offs,
                             float* __restrict__ dinv, int* __restrict__ sortedRow,
                             const float* __restrict__ x,
                             const unsigned short* __restrict__ Wh,
                             const unsigned short* __restrict__ Wl,
                             char* __restrict__ t0base, int t0stride) {
    __shared__ __align__(16) char L[49152];
    const int tid = threadIdx.x;

    if (blockIdx.x < NBKT) {                     // ---- csr ----
        int* lcnt = (int*)L;                     // 512
        int* sA   = lcnt + 512;                  // 512
        int* sB   = sA + 512;                    // 512
        int* lcur = sB + 512;                    // 512
        int* red  = lcur + 512;                  // 256
        const int b = blockIdx.x, n0 = b << BSH;
        // self-computed bucket base: prefix over gcur[0..b)
        red[tid] = (tid < b) ? gcur[tid] : 0;
        __syncthreads();
        for (int d = 128; d > 0; d >>= 1) {
            if (tid < d) red[tid] += red[tid + d];
            __syncthreads();
        }
        const int base = red[0];
        const int nb = gcur[b];
        lcnt[tid] = 0; lcnt[tid + 256] = 0;
        __syncthreads();
        const u64* ep = entries + (size_t)b * BCAP;
        for (int i = tid; i < nb; i += 256)
            atomicAdd(&lcnt[(int)(ep[i] >> 32) - n0], 1);
        __syncthreads();
        sA[tid] = lcnt[tid]; sA[tid + 256] = lcnt[tid + 256];
        __syncthreads();
        int* src = sA; int* dst = sB;
        for (int d = 1; d < 512; d <<= 1) {
            #pragma unroll
            for (int k = tid; k < 512; k += 256)
                dst[k] = src[k] + ((k >= d) ? src[k - d] : 0);
            __syncthreads();
            int* t = src; src = dst; dst = t;
        }
        #pragma unroll
        for (int k = tid; k < 512; k += 256) {
            int excl = src[k] - lcnt[k];
            lcur[k] = excl;
            int node = n0 + k;
            if (node < N_NODES) {
                offs[node] = base + excl;
                cnt[node]  = lcnt[k];
                dinv[node] = rsqrtf((float)(lcnt[k] + 1));   // +1 self loop
            }
        }
        __syncthreads();
        for (int i = tid; i < nb; i += 256) {
            u64 pk = ep[i];
            int local = (int)(pk >> 32) - n0;
            int p = base + atomicAdd(&lcur[local], 1);
            sortedRow[p] = (int)(pk & 0xFFFFFFFFu);
        }
        return;
    }

    // ---- gemm1: 4 waves x 16 nodes (64 nodes/block) ----
    const int bid = blockIdx.x - NBKT;
    const int wave = tid >> 6, lane = tid & 63;
    const int lrow = lane & 15, q4 = lane >> 4;
    const int swz = (lrow & 7) << 4;
    const int n0 = bid * 64;

    bf16x8 b[8];
    {
        int node = n0 + wave * 16 + lrow;
        int nc = node > N_NODES - 1 ? N_NODES - 1 : node;
        const float* xp = x + (size_t)nc * 256 + q4 * 8;
        #pragma unroll
        for (int ks = 0; ks < 8; ks++) {
            float4 p0 = *(const float4*)(xp + ks * 32);
            float4 p1 = *(const float4*)(xp + ks * 32 + 4);
            b[ks] = packhi(p0, p1);
        }
    }

    int sgo[4], slo[4];
    #pragma unroll
    for (int j = 0; j < 4; j++) {
        int u = tid + 256 * j;
        int col = (u >> 5) & 15, k8 = (u & 31) * 8;
        sgo[j] = col * 256 + k8;
        slo[j] = (j >= 2 ? 8192 : 0) + ((col * 512 + k8 * 2) ^ ((col & 7) << 4));
    }

    {   // stage ct 0
        int4 sw[4];
        #pragma unroll
        for (int j = 0; j < 4; j++)
            sw[j] = *(const int4*)((j >= 2 ? Wl : Wh) + sgo[j]);
        #pragma unroll
        for (int j = 0; j < 4; j++)
            *(int4*)(L + slo[j]) = sw[j];
    }
    __syncthreads();

    #pragma unroll
    for (int ct = 0; ct < 8; ct++) {
        int4 sw[4];
        if (ct < 7) {
            #pragma unroll
            for (int j = 0; j < 4; j++)
                sw[j] = *(const int4*)((j >= 2 ? Wl : Wh) + (ct + 1) * 16 * 256 + sgo[j]);
        }
        const char* bufp = L + (ct & 1) * 16384;
        f32x4 acc = {};
        #pragma unroll
        for (int hl = 0; hl < 2; hl++) {
            bf16x8 w[8];
            #pragma unroll
            for (int ks = 0; ks < 8; ks++)
                w[ks] = *(const bf16x8*)(bufp + hl * 8192 +
                        ((lrow * 512 + ks * 64 + q4 * 16) ^ swz));
            #pragma unroll
            for (int ks = 0; ks < 8; ks++)
                acc = MFMA16(w[ks], b[ks], acc);
        }
        {
            int node_l = wave * 16 + lrow;
            int a = (node_l * 256 + ct * 32 + q4 * 8) ^ ((node_l & 7) << 4);
            ushort4 p = make_ushort4(f2bf(acc[0]), f2bf(acc[1]),
                                     f2bf(acc[2]), f2bf(acc[3]));
            *(ushort4*)(L + 32768 + a) = p;
        }
        if (ct < 7) {
            #pragma unroll
            for (int j = 0; j < 4; j++)
                *(int4*)(L + (((ct + 1) & 1) * 16384) + slo[j]) = sw[j];
            __syncthreads();
        }
    }
    __syncthreads();
    #pragma unroll
    for (int it = 0; it < 4; it++) {
        int linear = it * 4096 + tid * 16;
        int node_l = linear >> 8, off = linear & 255;
        int4 v = *(const int4*)(L + 32768 + (linear ^ ((node_l & 7) << 4)));
        int node = n0 + node_l;
        if (node < N_NODES)
            *(int4*)(t0base + (size_t)node * t0stride + off) = v;
    }
}

// ---------------- aggregation: scalarized edges; separate src/dst strides --------------

template <int EPI>
__launch_bounds__(256)
__global__ void agg_bf16(const char* __restrict__ srcBase, char* __restrict__ dstBase,
                         int srcStride, int dstStride,
                         const int* __restrict__ offs, const int* __restrict__ cnt,
                         const int* __restrict__ sortedRow, const float* __restrict__ dinv,
                         const float* __restrict__ bias) {
    const int n = blockIdx.x * 4 + (threadIdx.x >> 6);
    const int lane = threadIdx.x & 63;
    const int laneB = lane * 4;
    const float dn = dinv[n];
    unsigned int u = *(const unsigned int*)(srcBase + (size_t)n * srcStride + laneB);
    const float ws = dn * dn;
    float acc0 = ws * bf_lo(u);
    float acc1 = ws * bf_hi(u);
    const int start = __builtin_amdgcn_readfirstlane(offs[n]);
    const int num   = __builtin_amdgcn_readfirstlane(cnt[n]);

    int i = 0;
    for (; i + 8 <= num; i += 8) {
        int myr = sortedRow[start + i + (lane & 7)];
        int rs[8];
        #pragma unroll
        for (int j = 0; j < 8; j++) rs[j] = __builtin_amdgcn_readlane(myr, j);
        unsigned int ue[8];
        #pragma unroll
        for (int j = 0; j < 8; j++) {
            const char* p = srcBase + (size_t)rs[j] * srcStride;   // SGPR base
            ue[j] = *(const unsigned int*)(p + laneB);
        }
        float w[8];
        #pragma unroll
        for (int j = 0; j < 8; j++) w[j] = dn * dinv[rs[j]];
        #pragma unroll
        for (int j = 0; j < 8; j++) {
            acc0 = fmaf(w[j], bf_lo(ue[j]), acc0);
            acc1 = fmaf(w[j], bf_hi(ue[j]), acc1);
        }
    }
    for (; i < num; i++) {
        int rsv = __builtin_amdgcn_readfirstlane(sortedRow[start + i]);
        const char* p = srcBase + (size_t)rsv * srcStride;
        unsigned int ue = *(const unsigned int*)(p + laneB);
        float w = dn * dinv[rsv];
        acc0 = fmaf(w, bf_lo(ue), acc0);
        acc1 = fmaf(w, bf_hi(ue), acc1);
    }

    if (EPI) {
        acc0 = fmaxf(acc0 + bias[2 * lane], 0.f);
        acc1 = fmaxf(acc1 + bias[2 * lane + 1], 0.f);
    }
    unsigned int o = (unsigned int)f2bf(acc0) | ((unsigned int)f2bf(acc1) << 16);
    *(unsigned int*)(dstBase + (size_t)n * dstStride + laneB) = o;
}

// ---------------- GEMM2: SPLIT=1 -> one output half per block (needs t2 not in outc) ---

template <int SPLIT>
__launch_bounds__(256, 4)
__global__ void gemm2_mfma(const unsigned short* __restrict__ Wh,
                           const unsigned short* __restrict__ Wl,
                           const float* __restrict__ bmu, const float* __restrict__ bsig,
                           const char* __restrict__ t2base, int t2stride,
                           char* __restrict__ outc) {
    __shared__ __align__(16) char L[16384];
    const int tid = threadIdx.x;
    const int wave = tid >> 6, lane = tid & 63;
    const int lrow = lane & 15, q4 = lane >> 4;
    const int swz = (lrow & 7) << 4;
    const int half = SPLIT ? (blockIdx.x & 1) : 0;
    const int nb2  = SPLIT ? (blockIdx.x >> 1) : blockIdx.x;
    const int n0 = nb2 * 64;
    const int CT = SPLIT ? 8 : 16;

    const int node = n0 + wave * 16 + lrow;
    const bool ok = node < N_NODES;
    bf16x8 b[4];
    {
        int nc = node > N_NODES - 1 ? N_NODES - 1 : node;
        const char* ap = t2base + (size_t)nc * t2stride + q4 * 16;
        #pragma unroll
        for (int ki = 0; ki < 4; ki++)
            b[ki] = *(const bf16x8*)(ap + ki * 64);
    }

    const int colS = tid >> 4, k8S = (tid & 15) * 8;
    const int sgo = colS * 128 + k8S;
    const int sloc = (colS * 256 + k8S * 2) ^ ((colS & 7) << 4);
    const int g0 = half * 8;                     // first 16-col tile of this block

    {   // stage tile g0
        int4 h = *(const int4*)(Wh + g0 * 2048 + sgo);
        int4 l = *(const int4*)(Wl + g0 * 2048 + sgo);
        *(int4*)(L + sloc) = h;
        *(int4*)(L + 4096 + sloc) = l;
    }
    __syncthreads();

    for (int ct = 0; ct < CT; ct++) {
        const int gct = g0 + ct;
        int4 swh, swl;
        if (ct < CT - 1) {
            swh = *(const int4*)(Wh + (gct + 1) * 2048 + sgo);
            swl = *(const int4*)(Wl + (gct + 1) * 2048 + sgo);
        }
        const char* bufp = L + (ct & 1) * 8192;
        f32x4 acc = {};
        #pragma unroll
        for (int hl = 0; hl < 2; hl++) {
            bf16x8 w[4];
            #pragma unroll
            for (int ki = 0; ki < 4; ki++)
                w[ki] = *(const bf16x8*)(bufp + hl * 4096 +
                        ((lrow * 256 + ki * 64 + q4 * 16) ^ swz));
            #pragma unroll
            for (int ki = 0; ki < 4; ki++)
                acc = MFMA16(w[ki], b[ki], acc);
        }
        const int f0 = (gct & 7) * 16 + q4 * 4;
        if (gct < 8) {                           // mu cols
            if (ok) {
                float4 bv = *(const float4*)(bmu + f0);
                f32x4 o = {acc[0] + bv.x, acc[1] + bv.y, acc[2] + bv.z, acc[3] + bv.w};
                ntstore4(outc + (size_t)node * ROWB + f0 * 4, o);
            }
        } else {                                 // sigma cols (fast softplus)
            if (ok) {
                float4 bv = *(const float4*)(bsig + f0);
                f32x4 o;
                #pragma unroll
                for (int q = 0; q < 4; q++)
                    o[q] = fast_sp(acc[q] + ((const float*)&bv)[q]);
                ntstore4(outc + HALFB + (size_t)node * ROWB + f0 * 4, o);
            }
        }
        if (ct < CT - 1) {
            char* nb = L + ((ct + 1) & 1) * 8192;
            *(int4*)(nb + sloc) = swh;
            *(int4*)(nb + 4096 + sloc) = swl;
            __syncthreads();
        }
    }
}

// ---------------- launch ----------------

extern "C" void kernel_launch(void* const* d_in, const int* in_sizes, int n_in,
                              void* d_out, int out_size, void* d_ws, size_t ws_size,
                              hipStream_t stream) {
    const float* x    = (const float*)d_in[0];
    const int*   ei   = (const int*)d_in[1];
    const int*   row  = ei;
    const int*   col  = ei + N_EDGES;
    const float* W0   = (const float*)d_in[2];
    const float* b0   = (const float*)d_in[3];
    const float* Wmu  = (const float*)d_in[4];
    const float* bmu  = (const float*)d_in[5];
    const float* Wsig = (const float*)d_in[6];
    const float* bsig = (const float*)d_in[7];
    char* outc = (char*)d_out;
    char* wsb  = (char*)d_ws;

    // tiered ws layout (256B-aligned fields); t2 placed early (cheapest dense win)
    size_t o = 0;
    auto take = [&](size_t nbytes) {
        size_t r = o; o += (nbytes + 255) & ~(size_t)255; return r;
    };
    size_t oW0h = take(65536), oW0l = take(65536);
    size_t oWmsh = take(65536), oWmsl = take(65536);
    size_t oGcur = take(NBKT * 4);
    size_t oCnt = take(N_NODES * 4), oOffs = take(N_NODES * 4), oDinv = take(N_NODES * 4);
    size_t oSort = take(N_EDGES * 4);
    size_t oT2 = take((size_t)N_NODES * 256);  size_t endT2 = o;   // ~33.5MB
    size_t oEnt = take((size_t)NBKT * BCAP * 8);
    size_t oT0 = take((size_t)N_NODES * 256);
    size_t oH  = take((size_t)N_NODES * 256);  size_t endAll = o;  // ~101MB
    const int tier = (ws_size >= endAll) ? 2 : (ws_size >= endT2 ? 1 : 0);

    unsigned short* W0h  = (unsigned short*)(wsb + oW0h);
    unsigned short* W0l  = (unsigned short*)(wsb + oW0l);
    unsigned short* Wmsh = (unsigned short*)(wsb + oWmsh);
    unsigned short* Wmsl = (unsigned short*)(wsb + oWmsl);
    int*   gcur      = (int*)(wsb + oGcur);
    int*   cnt       = (int*)(wsb + oCnt);
    int*   offs      = (int*)(wsb + oOffs);
    float* dinvp     = (float*)(wsb + oDinv);
    int*   sortedRow = (int*)(wsb + oSort);

    u64* entries = (tier == 2) ? (u64*)(wsb + oEnt) : (u64*)(outc + HALFB);
    char* t0b; int sT0;
    char* hb;  int sH;
    char* t2b; int sT2;
    if (tier == 2) { t0b = wsb + oT0; sT0 = 256; hb = wsb + oH; sH = 256; }
    else           { t0b = outc + 256; sT0 = ROWB; hb = outc + HALFB; sH = ROWB; }
    if (tier >= 1) { t2b = wsb + oT2; sT2 = 256; }
    else           { t2b = outc; sT2 = ROWB; }

    hipMemsetAsync(gcur, 0, NBKT * sizeof(int), stream);
    k1_prep_bin<<<PREPB + (N_EDGES + EPB - 1) / EPB, 256, 0, stream>>>(
        W0, Wmu, Wsig, W0h, W0l, Wmsh, Wmsl, row, col, gcur, entries);
    k2_csr_gemm1<<<NBKT + (N_NODES + 63) / 64, 256, 0, stream>>>(
        entries, gcur, cnt, offs, dinvp, sortedRow, x, W0h, W0l, t0b, sT0);
    agg_bf16<1><<<N_NODES / 4, 256, 0, stream>>>(t0b, hb, sT0, sH,
                                                 offs, cnt, sortedRow, dinvp, b0);
    agg_bf16<0><<<N_NODES / 4, 256, 0, stream>>>(hb, t2b, sH, sT2,
                                                 offs, cnt, sortedRow, dinvp, nullptr);
    if (tier >= 1)
        gemm2_mfma<1><<<2 * ((N_NODES + 63) / 64), 256, 0, stream>>>(
            Wmsh, Wmsl, bmu, bsig, t2b, sT2, outc);
    else
        gemm2_mfma<0><<<(N_NODES + 63) / 64, 256, 0, stream>>>(
            Wmsh, Wmsl, bmu, bsig, t2b, sT2, outc);
}